// Round 1
// baseline (336.478 us; speedup 1.0000x reference)
//
#include <hip/hip_runtime.h>

#define B_ 8
#define M_ 4096
#define E_ 1024
#define D_ 256
#define C_ 16

typedef unsigned short u16;
typedef float fv4 __attribute__((ext_vector_type(4)));
typedef short bh8 __attribute__((ext_vector_type(8)));

__device__ __forceinline__ float b2f(u16 v) { return __uint_as_float(((unsigned)v) << 16); }
__device__ __forceinline__ u16 f2b(float f) {
  unsigned u = __float_as_uint(f);
  return (u16)((u + 0x7FFFu + ((u >> 16) & 1u)) >> 16);
}
__device__ __forceinline__ unsigned pk2(float a, float b) {
  return (unsigned)f2b(a) | ((unsigned)f2b(b) << 16);
}

// ---------- transpose + f32->bf16 convert: src[R][Cc] f32 -> dst[Cc][R] bf16 ----------
__global__ __launch_bounds__(256) void k_tcvt(const float* __restrict__ src, u16* __restrict__ dst,
                                              int R, int Cc, long ss, long ds) {
  __shared__ unsigned tw[64][37];
  const float* s = src + (long)blockIdx.z * ss;
  u16* d = dst + (long)blockIdx.z * ds;
  int r0 = blockIdx.y * 64, c0 = blockIdx.x * 64;
  int t = threadIdx.x;
  int lr = t >> 2, lc = (t & 3) << 4;
  const float4* sp = reinterpret_cast<const float4*>(s + (long)(r0 + lr) * Cc + (c0 + lc));
#pragma unroll
  for (int i = 0; i < 4; ++i) {
    float4 v = sp[i];
    tw[lr][(lc >> 1) + i * 2]     = pk2(v.x, v.y);
    tw[lr][(lc >> 1) + i * 2 + 1] = pk2(v.z, v.w);
  }
  __syncthreads();
  int oc = t >> 2, orr = (t & 3) << 4;
  alignas(16) u16 buf[16];
#pragma unroll
  for (int i = 0; i < 16; ++i) {
    unsigned wv = tw[orr + i][oc >> 1];
    buf[i] = (u16)((oc & 1) ? (wv >> 16) : (wv & 0xffffu));
  }
  u16* dp = d + (long)(c0 + oc) * R + (r0 + orr);
  reinterpret_cast<int4*>(dp)[0] = reinterpret_cast<const int4*>(buf)[0];
  reinterpret_cast<int4*>(dp)[1] = reinterpret_cast<const int4*>(buf)[1];
}

// ---------- convert two f32 arrays to bf16 (Wa, Wp) ----------
__global__ __launch_bounds__(256) void k_cvt2(const float* __restrict__ a, u16* __restrict__ da,
                                              const float* __restrict__ b, u16* __restrict__ db, int n) {
  int i = (blockIdx.x * 256 + threadIdx.x) * 4;
  if (i >= n) return;
  float4 v = *reinterpret_cast<const float4*>(a + i);
  float4 u = *reinterpret_cast<const float4*>(b + i);
  da[i] = f2b(v.x); da[i + 1] = f2b(v.y); da[i + 2] = f2b(v.z); da[i + 3] = f2b(v.w);
  db[i] = f2b(u.x); db[i + 1] = f2b(u.y); db[i + 2] = f2b(u.z); db[i + 3] = f2b(u.w);
}

// ---------- generic TN GEMM: C[r][c] = sum_k A[r][k]*Bt[c][k], bf16 in, f32 acc ----------
// BM=128, BN=64, BK=64, 256 threads (4 waves, wave tile 64x32).
// MODE 0: write bf16 C. MODE 1: outEF = alpha*edge + (1-alpha)*C (f32).
template <int MODE>
__global__ __launch_bounds__(256, 2) void k_gemm(
    const u16* __restrict__ A, long Abstr,
    const u16* __restrict__ Bt, long Bbstr,
    int K, int R, int Cc,
    u16* __restrict__ outG,
    const float* __restrict__ edge, const float* __restrict__ alphap,
    float* __restrict__ outEF) {
  __shared__ u16 As[128][72];
  __shared__ u16 Bs[64][72];
  int b = blockIdx.z;
  const u16* Ab = A + (long)b * Abstr;
  const u16* Bb = Bt + (long)b * Bbstr;
  int r0 = blockIdx.y * 128, c0 = blockIdx.x * 64;
  int t = threadIdx.x, l = t & 63, w = t >> 6;
  int wr = w >> 1, wc = w & 1;
  int l15 = l & 15, lg = l >> 4;
  fv4 acc[4][2] = {};

  int art = t >> 1, akt = (t & 1) * 32;
  int brt = t >> 2, bkt = (t & 3) * 16;
  const u16* gap = Ab + (long)(r0 + art) * K + akt;
  const u16* gbp = Bb + (long)(c0 + brt) * K + bkt;

  for (int k0 = 0; k0 < K; k0 += 64) {
    int4 a0 = reinterpret_cast<const int4*>(gap + k0)[0];
    int4 a1 = reinterpret_cast<const int4*>(gap + k0)[1];
    int4 a2 = reinterpret_cast<const int4*>(gap + k0)[2];
    int4 a3 = reinterpret_cast<const int4*>(gap + k0)[3];
    int4 b0 = reinterpret_cast<const int4*>(gbp + k0)[0];
    int4 b1 = reinterpret_cast<const int4*>(gbp + k0)[1];
    __syncthreads();
    reinterpret_cast<int4*>(&As[art][akt])[0] = a0;
    reinterpret_cast<int4*>(&As[art][akt])[1] = a1;
    reinterpret_cast<int4*>(&As[art][akt])[2] = a2;
    reinterpret_cast<int4*>(&As[art][akt])[3] = a3;
    reinterpret_cast<int4*>(&Bs[brt][bkt])[0] = b0;
    reinterpret_cast<int4*>(&Bs[brt][bkt])[1] = b1;
    __syncthreads();
#pragma unroll
    for (int kk = 0; kk < 2; ++kk) {
      bh8 af[4], bfr[2];
#pragma unroll
      for (int i = 0; i < 4; ++i)
        af[i] = *reinterpret_cast<const bh8*>(&As[wr * 64 + i * 16 + l15][kk * 32 + lg * 8]);
#pragma unroll
      for (int j = 0; j < 2; ++j)
        bfr[j] = *reinterpret_cast<const bh8*>(&Bs[wc * 32 + j * 16 + l15][kk * 32 + lg * 8]);
#pragma unroll
      for (int i = 0; i < 4; ++i)
#pragma unroll
        for (int j = 0; j < 2; ++j)
          acc[i][j] = __builtin_amdgcn_mfma_f32_16x16x32_bf16(af[i], bfr[j], acc[i][j], 0, 0, 0);
    }
  }
  float al = 0.f, oneal = 0.f;
  if (MODE == 1) { al = *alphap; oneal = 1.0f - al; }
#pragma unroll
  for (int i = 0; i < 4; ++i)
#pragma unroll
    for (int j = 0; j < 2; ++j)
#pragma unroll
      for (int q = 0; q < 4; ++q) {
        int row = r0 + wr * 64 + i * 16 + lg * 4 + q;
        int col = c0 + wc * 32 + j * 16 + l15;
        long idx = ((long)b * R + row) * Cc + col;
        if (MODE == 0) outG[idx] = f2b(acc[i][j][q]);
        else outEF[idx] = al * edge[idx] + oneal * acc[i][j][q];
      }
}

// ---------- S = G @ Wa^T per (batch, 64-d chunk) + column softmax stats over e ----------
__global__ __launch_bounds__(256, 1) void k_sstats(
    const u16* __restrict__ Gb, const u16* __restrict__ Wab,
    float* __restrict__ S, float* __restrict__ mx, float* __restrict__ sm) {
  __shared__ u16 Bs[64][264];
  __shared__ u16 As[64][72];
  __shared__ float cmax[2][64];
  __shared__ float rmax[64];
  __shared__ float rsum[4][64];
  int dc = blockIdx.x, b = blockIdx.y;
  int c0 = dc * 64;
  int t = threadIdx.x, l = t & 63, w = t >> 6;
  int wr = w >> 1, wc = w & 1;
  int l15 = l & 15, lg = l >> 4;
  {
    int row = t >> 2, kof = (t & 3) * 64;
    const int4* g = reinterpret_cast<const int4*>(Wab + (long)(c0 + row) * D_ + kof);
#pragma unroll
    for (int i = 0; i < 8; ++i)
      reinterpret_cast<int4*>(&Bs[row][kof])[i] = g[i];
  }
  if (t < 64) rmax[t] = -3.0e38f;
  __syncthreads();

  for (int et = 0; et < 16; ++et) {
    int e0 = et * 64;
    fv4 acc[2][2] = {};
#pragma unroll 1
    for (int ks = 0; ks < 4; ++ks) {
      int row = t >> 2, kof = (t & 3) * 16;
      const int4* g = reinterpret_cast<const int4*>(Gb + ((long)b * E_ + e0 + row) * D_ + ks * 64 + kof);
      int4 v0 = g[0], v1 = g[1];
      __syncthreads();
      reinterpret_cast<int4*>(&As[row][kof])[0] = v0;
      reinterpret_cast<int4*>(&As[row][kof])[1] = v1;
      __syncthreads();
#pragma unroll
      for (int kk = 0; kk < 2; ++kk) {
        bh8 af[2], bfr[2];
#pragma unroll
        for (int i = 0; i < 2; ++i)
          af[i] = *reinterpret_cast<const bh8*>(&As[wr * 32 + i * 16 + l15][kk * 32 + lg * 8]);
#pragma unroll
        for (int j = 0; j < 2; ++j)
          bfr[j] = *reinterpret_cast<const bh8*>(&Bs[wc * 32 + j * 16 + l15][ks * 64 + kk * 32 + lg * 8]);
#pragma unroll
        for (int i = 0; i < 2; ++i)
#pragma unroll
          for (int j = 0; j < 2; ++j)
            acc[i][j] = __builtin_amdgcn_mfma_f32_16x16x32_bf16(af[i], bfr[j], acc[i][j], 0, 0, 0);
      }
    }
    float lmax0 = -3.0e38f, lmax1 = -3.0e38f;
#pragma unroll
    for (int i = 0; i < 2; ++i)
#pragma unroll
      for (int q = 0; q < 4; ++q) {
        int row = e0 + wr * 32 + i * 16 + lg * 4 + q;
        float v0 = acc[i][0][q];
        float v1 = acc[i][1][q];
        S[((long)b * E_ + row) * D_ + (c0 + wc * 32 + l15)] = v0;
        S[((long)b * E_ + row) * D_ + (c0 + wc * 32 + 16 + l15)] = v1;
        lmax0 = fmaxf(lmax0, v0);
        lmax1 = fmaxf(lmax1, v1);
      }
    lmax0 = fmaxf(lmax0, __shfl_xor(lmax0, 16));
    lmax0 = fmaxf(lmax0, __shfl_xor(lmax0, 32));
    lmax1 = fmaxf(lmax1, __shfl_xor(lmax1, 16));
    lmax1 = fmaxf(lmax1, __shfl_xor(lmax1, 32));
    if (l < 16) {
      cmax[wr][wc * 32 + l] = lmax0;
      cmax[wr][wc * 32 + 16 + l] = lmax1;
    }
    __syncthreads();
    if (t < 64) rmax[t] = fmaxf(rmax[t], fmaxf(cmax[0][t], cmax[1][t]));
    __syncthreads();
  }
  // pass 2: exp-sum per column (S for our columns was written entirely by this block)
  int cl = t & 63, g4 = t >> 6;
  float cm = rmax[cl];
  float ps = 0.f;
  for (int e = g4; e < E_; e += 4)
    ps += __expf(S[((long)b * E_ + e) * D_ + c0 + cl] - cm);
  rsum[g4][cl] = ps;
  __syncthreads();
  if (t < 64) {
    mx[b * D_ + c0 + t] = rmax[t];
    sm[b * D_ + c0 + t] = rsum[0][t] + rsum[1][t] + rsum[2][t] + rsum[3][t];
  }
}

// ---------- H = G * softmax_e(S) in bf16 ----------
__global__ __launch_bounds__(256) void k_H(const u16* __restrict__ G, const float* __restrict__ S,
                                           const float* __restrict__ mx, const float* __restrict__ sm,
                                           u16* __restrict__ H) {
  long i = ((long)blockIdx.x * 256 + threadIdx.x) * 8;
  bh8 gv = *reinterpret_cast<const bh8*>(G + i);
  int d0 = (int)(i & (D_ - 1));
  int b = (int)(i >> 18);  // E_*D_ = 2^18
  const float* Sp = S + i;
  const float* mxp = mx + b * D_ + d0;
  const float* smp = sm + b * D_ + d0;
  bh8 hv;
#pragma unroll
  for (int j = 0; j < 8; ++j) {
    float a = __expf(Sp[j] - mxp[j]) / smp[j];
    hv[j] = (short)f2b(b2f((u16)gv[j]) * a);
  }
  *reinterpret_cast<bh8*>(H + i) = hv;
}

// ---------- z[b][e] = ef[b][e][:] . attw ----------
__global__ __launch_bounds__(256) void k_z(const float* __restrict__ ef, const float* __restrict__ attw,
                                           float* __restrict__ z) {
  int b = blockIdx.y, e0 = blockIdx.x * 64;
  int w = threadIdx.x >> 6, l = threadIdx.x & 63;
  float4 wv = *reinterpret_cast<const float4*>(attw + l * 4);
  for (int e = e0 + w; e < e0 + 64; e += 4) {
    float4 v = *reinterpret_cast<const float4*>(ef + ((long)b * E_ + e) * D_ + l * 4);
    float p = v.x * wv.x + v.y * wv.y + v.z * wv.z + v.w * wv.w;
#pragma unroll
    for (int off = 32; off; off >>= 1) p += __shfl_down(p, off);
    if (l == 0) z[b * E_ + e] = p;
  }
}

// ---------- softmax over e of z -> az ----------
__global__ __launch_bounds__(256) void k_zsm(const float* __restrict__ z, float* __restrict__ az) {
  int b = blockIdx.x, t = threadIdx.x;
  __shared__ float wred[4];
  float4 v = *reinterpret_cast<const float4*>(z + b * E_ + t * 4);
  float m = fmaxf(fmaxf(v.x, v.y), fmaxf(v.z, v.w));
#pragma unroll
  for (int off = 32; off; off >>= 1) m = fmaxf(m, __shfl_xor(m, off));
  if ((t & 63) == 0) wred[t >> 6] = m;
  __syncthreads();
  m = fmaxf(fmaxf(wred[0], wred[1]), fmaxf(wred[2], wred[3]));
  float e0 = __expf(v.x - m), e1 = __expf(v.y - m), e2 = __expf(v.z - m), e3 = __expf(v.w - m);
  float s = e0 + e1 + e2 + e3;
#pragma unroll
  for (int off = 32; off; off >>= 1) s += __shfl_xor(s, off);
  __syncthreads();
  if ((t & 63) == 0) wred[t >> 6] = s;
  __syncthreads();
  s = wred[0] + wred[1] + wred[2] + wred[3];
  float inv = 1.0f / s;
  float4 o;
  o.x = e0 * inv; o.y = e1 * inv; o.z = e2 * inv; o.w = e3 * inv;
  *reinterpret_cast<float4*>(az + b * E_ + t * 4) = o;
}

// ---------- pooled[b][d] = sum_e az[b][e] * ef[b][e][d] ----------
__global__ __launch_bounds__(256) void k_pooled(const float* __restrict__ ef, const float* __restrict__ az,
                                                float* __restrict__ pooled) {
  int b = blockIdx.y;
  int d = blockIdx.x * 64 + (threadIdx.x & 63);
  int g = threadIdx.x >> 6;
  float a = 0.f;
  for (int e = g; e < E_; e += 4)
    a += az[b * E_ + e] * ef[((long)b * E_ + e) * D_ + d];
  __shared__ float ps[4][64];
  ps[g][threadIdx.x & 63] = a;
  __syncthreads();
  if (threadIdx.x < 64)
    pooled[b * D_ + blockIdx.x * 64 + threadIdx.x] =
        ps[0][threadIdx.x] + ps[1][threadIdx.x] + ps[2][threadIdx.x] + ps[3][threadIdx.x];
}

// ---------- out = pooled@proj^T + b ; logits = out@fc^T + fcb ----------
__global__ __launch_bounds__(256) void k_out(const float* __restrict__ pooled,
                                             const float* __restrict__ projw, const float* __restrict__ projb,
                                             const float* __restrict__ fcw, const float* __restrict__ fcb,
                                             float* __restrict__ outp) {
  int b = blockIdx.x, t = threadIdx.x;
  __shared__ float pl[D_], ov[D_];
  pl[t] = pooled[b * D_ + t];
  __syncthreads();
  float o = projb[t];
  for (int d = 0; d < D_; ++d) o += projw[t * D_ + d] * pl[d];
  ov[t] = o;
  __syncthreads();
  if (t < C_) {
    float lg = fcb[t];
    for (int d = 0; d < D_; ++d) lg += fcw[t * D_ + d] * ov[d];
    outp[b * C_ + t] = lg;
  }
}

extern "C" void kernel_launch(void* const* d_in, const int* in_sizes, int n_in,
                              void* d_out, int out_size, void* d_ws, size_t ws_size,
                              hipStream_t stream) {
  const float* node  = (const float*)d_in[0];
  const float* edge  = (const float*)d_in[1];
  const float* inc   = (const float*)d_in[2];
  const float* Wa    = (const float*)d_in[3];
  const float* Wp    = (const float*)d_in[4];
  const float* alpha = (const float*)d_in[5];
  const float* attw  = (const float*)d_in[6];
  const float* projw = (const float*)d_in[7];
  const float* projb = (const float*)d_in[8];
  const float* fcw   = (const float*)d_in[9];
  const float* fcb   = (const float*)d_in[10];
  float* outp = (float*)d_out;

  char* wsp = (char*)d_ws;
  size_t off = 0;
  auto alloc = [&](size_t bytes) {
    char* p = wsp + off;
    off += (bytes + 255) & ~(size_t)255;
    return (void*)p;
  };
  u16* incT   = (u16*)alloc((size_t)B_ * E_ * M_ * 2);
  u16* nfT    = (u16*)alloc((size_t)B_ * D_ * M_ * 2);
  u16* Wab    = (u16*)alloc((size_t)D_ * D_ * 2);
  u16* Wpb    = (u16*)alloc((size_t)D_ * D_ * 2);
  u16* G      = (u16*)alloc((size_t)B_ * E_ * D_ * 2);
  float* S    = (float*)alloc((size_t)B_ * E_ * D_ * 4);
  u16* H      = (u16*)alloc((size_t)B_ * E_ * D_ * 2);
  float* ef   = (float*)alloc((size_t)B_ * E_ * D_ * 4);
  float* mx   = (float*)alloc((size_t)B_ * D_ * 4);
  float* sm   = (float*)alloc((size_t)B_ * D_ * 4);
  float* z    = (float*)alloc((size_t)B_ * E_ * 4);
  float* az   = (float*)alloc((size_t)B_ * E_ * 4);
  float* pooled = (float*)alloc((size_t)B_ * D_ * 4);

  // 1. transpose+convert inc -> incT [b][e][m] bf16
  k_tcvt<<<dim3(E_ / 64, M_ / 64, B_), 256, 0, stream>>>(inc, incT, M_, E_, (long)M_ * E_, (long)E_ * M_);
  // 2. transpose+convert node_feats -> nfT [b][d][m] bf16
  k_tcvt<<<dim3(D_ / 64, M_ / 64, B_), 256, 0, stream>>>(node, nfT, M_, D_, (long)M_ * D_, (long)D_ * M_);
  // 3. convert Wa, Wp
  k_cvt2<<<dim3(D_ * D_ / 1024), 256, 0, stream>>>(Wa, Wab, Wp, Wpb, D_ * D_);
  // 4. G[b] = incT[b] @ nfT[b]^T  (i.e. inc^T @ nf), bf16 out
  k_gemm<0><<<dim3(D_ / 64, E_ / 128, B_), 256, 0, stream>>>(
      incT, (long)E_ * M_, nfT, (long)D_ * M_, M_, E_, D_, G, nullptr, nullptr, nullptr);
  // 5. S = G @ Wa^T + column softmax stats over e
  k_sstats<<<dim3(D_ / 64, B_), 256, 0, stream>>>(G, Wab, S, mx, sm);
  // 6. H = G * softmax_e(S)
  k_H<<<dim3((B_ * E_ * D_) / (256 * 8)), 256, 0, stream>>>(G, S, mx, sm, H);
  // 7. ef = alpha*edge + (1-alpha) * (H @ Wp^T)
  k_gemm<1><<<dim3(D_ / 64, E_ / 128, B_), 256, 0, stream>>>(
      H, (long)E_ * D_, Wpb, 0L, D_, E_, D_, nullptr, edge, alpha, ef);
  // 8-11. edge attention pooling + final projections
  k_z<<<dim3(E_ / 64, B_), 256, 0, stream>>>(ef, attw, z);
  k_zsm<<<dim3(B_), 256, 0, stream>>>(z, az);
  k_pooled<<<dim3(D_ / 64, B_), 256, 0, stream>>>(ef, az, pooled);
  k_out<<<dim3(B_), 256, 0, stream>>>(pooled, projw, projb, fcw, fcb, outp);
}

// Round 2
// 232.978 us; speedup vs baseline: 1.4442x; 1.4442x over previous
//
#include <hip/hip_runtime.h>

#define B_ 8
#define M_ 4096
#define E_ 1024
#define D_ 256
#define C_ 16

typedef unsigned short u16;
typedef float fv4 __attribute__((ext_vector_type(4)));
typedef short bh8 __attribute__((ext_vector_type(8)));

__device__ __forceinline__ float b2f(u16 v) { return __uint_as_float(((unsigned)v) << 16); }
__device__ __forceinline__ u16 f2b(float f) {
  unsigned u = __float_as_uint(f);
  return (u16)((u + 0x7FFFu + ((u >> 16) & 1u)) >> 16);
}
__device__ __forceinline__ unsigned pk2(float a, float b) {
  return (unsigned)f2b(a) | ((unsigned)f2b(b) << 16);
}

// ---------- transpose + f32->bf16 convert: src[R][Cc] f32 -> dst[Cc][R] bf16 ----------
__global__ __launch_bounds__(256) void k_tcvt(const float* __restrict__ src, u16* __restrict__ dst,
                                              int R, int Cc, long ss, long ds) {
  __shared__ unsigned tw[64][37];
  const float* s = src + (long)blockIdx.z * ss;
  u16* d = dst + (long)blockIdx.z * ds;
  int r0 = blockIdx.y * 64, c0 = blockIdx.x * 64;
  int t = threadIdx.x;
  int lr = t >> 2, lc = (t & 3) << 4;
  const float4* sp = reinterpret_cast<const float4*>(s + (long)(r0 + lr) * Cc + (c0 + lc));
#pragma unroll
  for (int i = 0; i < 4; ++i) {
    float4 v = sp[i];
    tw[lr][(lc >> 1) + i * 2]     = pk2(v.x, v.y);
    tw[lr][(lc >> 1) + i * 2 + 1] = pk2(v.z, v.w);
  }
  __syncthreads();
  int oc = t >> 2, orr = (t & 3) << 4;
  alignas(16) u16 buf[16];
#pragma unroll
  for (int i = 0; i < 16; ++i) {
    unsigned wv = tw[orr + i][oc >> 1];
    buf[i] = (u16)((oc & 1) ? (wv >> 16) : (wv & 0xffffu));
  }
  u16* dp = d + (long)(c0 + oc) * R + (r0 + orr);
  reinterpret_cast<int4*>(dp)[0] = reinterpret_cast<const int4*>(buf)[0];
  reinterpret_cast<int4*>(dp)[1] = reinterpret_cast<const int4*>(buf)[1];
}

// ---------- convert two f32 arrays to bf16 (Wa, Wp) ----------
__global__ __launch_bounds__(256) void k_cvt2(const float* __restrict__ a, u16* __restrict__ da,
                                              const float* __restrict__ b, u16* __restrict__ db, int n) {
  int i = (blockIdx.x * 256 + threadIdx.x) * 4;
  if (i >= n) return;
  float4 v = *reinterpret_cast<const float4*>(a + i);
  float4 u = *reinterpret_cast<const float4*>(b + i);
  da[i] = f2b(v.x); da[i + 1] = f2b(v.y); da[i + 2] = f2b(v.z); da[i + 3] = f2b(v.w);
  db[i] = f2b(u.x); db[i + 1] = f2b(u.y); db[i + 2] = f2b(u.z); db[i + 3] = f2b(u.w);
}

// ---------- generic TN GEMM: C[r][c] = sum_k A[r][k]*Bt[c][k], bf16 in, f32 acc ----------
// BM=128, BN=64, BK=64, 256 threads (4 waves, wave tile 64x32).
// Grid: 1D 256 blocks, decoded so the 4 column-blocks sharing an A panel land
// on the same XCD (flat%8 == XCD under round-robin dispatch).
// MODE 0: write bf16 C. MODE 1: outEF = alpha*edge + (1-alpha)*C (f32).
// MODE 2: write f32 C (raw).
template <int MODE>
__global__ __launch_bounds__(256, 2) void k_gemm(
    const u16* __restrict__ A, long Abstr,
    const u16* __restrict__ Bt, long Bbstr,
    int K, int R, int Cc,
    u16* __restrict__ outG,
    const float* __restrict__ edge, const float* __restrict__ alphap,
    float* __restrict__ outEF) {
  __shared__ u16 As[128][72];
  __shared__ u16 Bs[64][72];
  // swizzled decode: f = xcd + 8*(x + 4*(g>>3)), g = y + 8*z
  int f = blockIdx.x;
  int xcd = f & 7, s = f >> 3;
  int x = s & 3;
  int g = xcd | ((s >> 2) << 3);
  int y = g & 7, b = g >> 3;
  const u16* Ab = A + (long)b * Abstr;
  const u16* Bb = Bt + (long)b * Bbstr;
  int r0 = y * 128, c0 = x * 64;
  int t = threadIdx.x, l = t & 63, w = t >> 6;
  int wr = w >> 1, wc = w & 1;
  int l15 = l & 15, lg = l >> 4;
  fv4 acc[4][2] = {};

  int art = t >> 1, akt = (t & 1) * 32;
  int brt = t >> 2, bkt = (t & 3) * 16;
  const u16* gap = Ab + (long)(r0 + art) * K + akt;
  const u16* gbp = Bb + (long)(c0 + brt) * K + bkt;

  for (int k0 = 0; k0 < K; k0 += 64) {
    int4 a0 = reinterpret_cast<const int4*>(gap + k0)[0];
    int4 a1 = reinterpret_cast<const int4*>(gap + k0)[1];
    int4 a2 = reinterpret_cast<const int4*>(gap + k0)[2];
    int4 a3 = reinterpret_cast<const int4*>(gap + k0)[3];
    int4 b0 = reinterpret_cast<const int4*>(gbp + k0)[0];
    int4 b1 = reinterpret_cast<const int4*>(gbp + k0)[1];
    __syncthreads();
    reinterpret_cast<int4*>(&As[art][akt])[0] = a0;
    reinterpret_cast<int4*>(&As[art][akt])[1] = a1;
    reinterpret_cast<int4*>(&As[art][akt])[2] = a2;
    reinterpret_cast<int4*>(&As[art][akt])[3] = a3;
    reinterpret_cast<int4*>(&Bs[brt][bkt])[0] = b0;
    reinterpret_cast<int4*>(&Bs[brt][bkt])[1] = b1;
    __syncthreads();
#pragma unroll
    for (int kk = 0; kk < 2; ++kk) {
      bh8 af[4], bfr[2];
#pragma unroll
      for (int i = 0; i < 4; ++i)
        af[i] = *reinterpret_cast<const bh8*>(&As[wr * 64 + i * 16 + l15][kk * 32 + lg * 8]);
#pragma unroll
      for (int j = 0; j < 2; ++j)
        bfr[j] = *reinterpret_cast<const bh8*>(&Bs[wc * 32 + j * 16 + l15][kk * 32 + lg * 8]);
#pragma unroll
      for (int i = 0; i < 4; ++i)
#pragma unroll
        for (int j = 0; j < 2; ++j)
          acc[i][j] = __builtin_amdgcn_mfma_f32_16x16x32_bf16(af[i], bfr[j], acc[i][j], 0, 0, 0);
    }
  }
  float al = 0.f, oneal = 0.f;
  if (MODE == 1) { al = *alphap; oneal = 1.0f - al; }
#pragma unroll
  for (int i = 0; i < 4; ++i)
#pragma unroll
    for (int j = 0; j < 2; ++j)
#pragma unroll
      for (int q = 0; q < 4; ++q) {
        int row = r0 + wr * 64 + i * 16 + lg * 4 + q;
        int col = c0 + wc * 32 + j * 16 + l15;
        long idx = ((long)b * R + row) * Cc + col;
        if (MODE == 0) outG[idx] = f2b(acc[i][j][q]);
        else if (MODE == 1) outEF[idx] = al * edge[idx] + oneal * acc[i][j][q];
        else outEF[idx] = acc[i][j][q];
      }
}

// ---------- column stats stage 1: per-(b, seg of 256 e, d) max & expsum ----------
__global__ __launch_bounds__(256) void k_cstats1(const float* __restrict__ S,
                                                 float* __restrict__ mxp, float* __restrict__ smp) {
  int dl = threadIdx.x & 63;
  int d = blockIdx.x * 64 + dl;
  int seg = blockIdx.y, b = blockIdx.z;
  int g = threadIdx.x >> 6;
  __shared__ float red[4][64];
  const float* Sp = S + ((long)b * E_ + seg * 256) * D_ + d;
  float m = -3.0e38f;
  for (int e = g; e < 256; e += 4) m = fmaxf(m, Sp[(long)e * D_]);
  red[g][dl] = m;
  __syncthreads();
  m = fmaxf(fmaxf(red[0][dl], red[1][dl]), fmaxf(red[2][dl], red[3][dl]));
  float sum = 0.f;
  for (int e = g; e < 256; e += 4) sum += __expf(Sp[(long)e * D_] - m);
  __syncthreads();
  red[g][dl] = sum;
  __syncthreads();
  if (threadIdx.x < 64) {
    float ss = red[0][dl] + red[1][dl] + red[2][dl] + red[3][dl];
    int idx = (b * 4 + seg) * D_ + d;
    mxp[idx] = m;
    smp[idx] = ss;
  }
}

// ---------- column stats stage 2: combine 4 segments ----------
__global__ __launch_bounds__(256) void k_cstats2(const float* __restrict__ mxp, const float* __restrict__ smp,
                                                 float* __restrict__ mx, float* __restrict__ sm) {
  int i = blockIdx.x * 256 + threadIdx.x;  // over B_*D_
  int b = i >> 8, d = i & 255;
  float m0 = mxp[(b * 4 + 0) * D_ + d], m1 = mxp[(b * 4 + 1) * D_ + d];
  float m2 = mxp[(b * 4 + 2) * D_ + d], m3 = mxp[(b * 4 + 3) * D_ + d];
  float m = fmaxf(fmaxf(m0, m1), fmaxf(m2, m3));
  float s = smp[(b * 4 + 0) * D_ + d] * __expf(m0 - m) + smp[(b * 4 + 1) * D_ + d] * __expf(m1 - m) +
            smp[(b * 4 + 2) * D_ + d] * __expf(m2 - m) + smp[(b * 4 + 3) * D_ + d] * __expf(m3 - m);
  mx[i] = m;
  sm[i] = s;
}

// ---------- H = G * softmax_e(S) in bf16 ----------
__global__ __launch_bounds__(256) void k_H(const u16* __restrict__ G, const float* __restrict__ S,
                                           const float* __restrict__ mx, const float* __restrict__ sm,
                                           u16* __restrict__ H) {
  long i = ((long)blockIdx.x * 256 + threadIdx.x) * 8;
  bh8 gv = *reinterpret_cast<const bh8*>(G + i);
  int d0 = (int)(i & (D_ - 1));
  int b = (int)(i >> 18);  // E_*D_ = 2^18
  const float* Sp = S + i;
  const float* mxp = mx + b * D_ + d0;
  const float* smp = sm + b * D_ + d0;
  bh8 hv;
#pragma unroll
  for (int j = 0; j < 8; ++j) {
    float a = __expf(Sp[j] - mxp[j]) / smp[j];
    hv[j] = (short)f2b(b2f((u16)gv[j]) * a);
  }
  *reinterpret_cast<bh8*>(H + i) = hv;
}

// ---------- z[b][e] = ef[b][e][:] . attw ----------
__global__ __launch_bounds__(256) void k_z(const float* __restrict__ ef, const float* __restrict__ attw,
                                           float* __restrict__ z) {
  int b = blockIdx.y, e0 = blockIdx.x * 64;
  int w = threadIdx.x >> 6, l = threadIdx.x & 63;
  float4 wv = *reinterpret_cast<const float4*>(attw + l * 4);
  for (int e = e0 + w; e < e0 + 64; e += 4) {
    float4 v = *reinterpret_cast<const float4*>(ef + ((long)b * E_ + e) * D_ + l * 4);
    float p = v.x * wv.x + v.y * wv.y + v.z * wv.z + v.w * wv.w;
#pragma unroll
    for (int off = 32; off; off >>= 1) p += __shfl_down(p, off);
    if (l == 0) z[b * E_ + e] = p;
  }
}

// ---------- softmax over e of z -> az ----------
__global__ __launch_bounds__(256) void k_zsm(const float* __restrict__ z, float* __restrict__ az) {
  int b = blockIdx.x, t = threadIdx.x;
  __shared__ float wred[4];
  float4 v = *reinterpret_cast<const float4*>(z + b * E_ + t * 4);
  float m = fmaxf(fmaxf(v.x, v.y), fmaxf(v.z, v.w));
#pragma unroll
  for (int off = 32; off; off >>= 1) m = fmaxf(m, __shfl_xor(m, off));
  if ((t & 63) == 0) wred[t >> 6] = m;
  __syncthreads();
  m = fmaxf(fmaxf(wred[0], wred[1]), fmaxf(wred[2], wred[3]));
  float e0 = __expf(v.x - m), e1 = __expf(v.y - m), e2 = __expf(v.z - m), e3 = __expf(v.w - m);
  float s = e0 + e1 + e2 + e3;
#pragma unroll
  for (int off = 32; off; off >>= 1) s += __shfl_xor(s, off);
  __syncthreads();
  if ((t & 63) == 0) wred[t >> 6] = s;
  __syncthreads();
  s = wred[0] + wred[1] + wred[2] + wred[3];
  float inv = 1.0f / s;
  float4 o;
  o.x = e0 * inv; o.y = e1 * inv; o.z = e2 * inv; o.w = e3 * inv;
  *reinterpret_cast<float4*>(az + b * E_ + t * 4) = o;
}

// ---------- pooled[b][d] = sum_e az[b][e] * ef[b][e][d] ----------
__global__ __launch_bounds__(256) void k_pooled(const float* __restrict__ ef, const float* __restrict__ az,
                                                float* __restrict__ pooled) {
  int b = blockIdx.y;
  int d = blockIdx.x * 64 + (threadIdx.x & 63);
  int g = threadIdx.x >> 6;
  float a = 0.f;
  for (int e = g; e < E_; e += 4)
    a += az[b * E_ + e] * ef[((long)b * E_ + e) * D_ + d];
  __shared__ float ps[4][64];
  ps[g][threadIdx.x & 63] = a;
  __syncthreads();
  if (threadIdx.x < 64)
    pooled[b * D_ + blockIdx.x * 64 + threadIdx.x] =
        ps[0][threadIdx.x] + ps[1][threadIdx.x] + ps[2][threadIdx.x] + ps[3][threadIdx.x];
}

// ---------- out = pooled@proj^T + b ; logits = out@fc^T + fcb ----------
__global__ __launch_bounds__(256) void k_out(const float* __restrict__ pooled,
                                             const float* __restrict__ projw, const float* __restrict__ projb,
                                             const float* __restrict__ fcw, const float* __restrict__ fcb,
                                             float* __restrict__ outp) {
  int b = blockIdx.x, t = threadIdx.x;
  __shared__ float pl[D_], ov[D_];
  pl[t] = pooled[b * D_ + t];
  __syncthreads();
  float o = projb[t];
  for (int d = 0; d < D_; ++d) o += projw[t * D_ + d] * pl[d];
  ov[t] = o;
  __syncthreads();
  if (t < C_) {
    float lg = fcb[t];
    for (int d = 0; d < D_; ++d) lg += fcw[t * D_ + d] * ov[d];
    outp[b * C_ + t] = lg;
  }
}

extern "C" void kernel_launch(void* const* d_in, const int* in_sizes, int n_in,
                              void* d_out, int out_size, void* d_ws, size_t ws_size,
                              hipStream_t stream) {
  const float* node  = (const float*)d_in[0];
  const float* edge  = (const float*)d_in[1];
  const float* inc   = (const float*)d_in[2];
  const float* Wa    = (const float*)d_in[3];
  const float* Wp    = (const float*)d_in[4];
  const float* alpha = (const float*)d_in[5];
  const float* attw  = (const float*)d_in[6];
  const float* projw = (const float*)d_in[7];
  const float* projb = (const float*)d_in[8];
  const float* fcw   = (const float*)d_in[9];
  const float* fcb   = (const float*)d_in[10];
  float* outp = (float*)d_out;

  char* wsp = (char*)d_ws;
  size_t off = 0;
  auto alloc = [&](size_t bytes) {
    char* p = wsp + off;
    off += (bytes + 255) & ~(size_t)255;
    return (void*)p;
  };
  u16* incT   = (u16*)alloc((size_t)B_ * E_ * M_ * 2);
  u16* nfT    = (u16*)alloc((size_t)B_ * D_ * M_ * 2);
  u16* Wab    = (u16*)alloc((size_t)D_ * D_ * 2);
  u16* Wpb    = (u16*)alloc((size_t)D_ * D_ * 2);
  u16* G      = (u16*)alloc((size_t)B_ * E_ * D_ * 2);
  float* S    = (float*)alloc((size_t)B_ * E_ * D_ * 4);
  u16* H      = (u16*)alloc((size_t)B_ * E_ * D_ * 2);
  float* ef   = (float*)alloc((size_t)B_ * E_ * D_ * 4);
  float* mx   = (float*)alloc((size_t)B_ * D_ * 4);
  float* sm   = (float*)alloc((size_t)B_ * D_ * 4);
  float* mxp  = (float*)alloc((size_t)B_ * 4 * D_ * 4);
  float* smp  = (float*)alloc((size_t)B_ * 4 * D_ * 4);
  float* z    = (float*)alloc((size_t)B_ * E_ * 4);
  float* az   = (float*)alloc((size_t)B_ * E_ * 4);
  float* pooled = (float*)alloc((size_t)B_ * D_ * 4);

  // 1. transpose+convert inc -> incT [b][e][m] bf16
  k_tcvt<<<dim3(E_ / 64, M_ / 64, B_), 256, 0, stream>>>(inc, incT, M_, E_, (long)M_ * E_, (long)E_ * M_);
  // 2. transpose+convert node_feats -> nfT [b][d][m] bf16
  k_tcvt<<<dim3(D_ / 64, M_ / 64, B_), 256, 0, stream>>>(node, nfT, M_, D_, (long)M_ * D_, (long)D_ * M_);
  // 3. convert Wa, Wp
  k_cvt2<<<dim3(D_ * D_ / 1024), 256, 0, stream>>>(Wa, Wab, Wp, Wpb, D_ * D_);
  // 4. G[b] = incT[b] @ nfT[b]^T  (i.e. inc^T @ nf), bf16 out  [swizzled 1D grid]
  k_gemm<0><<<dim3(256), 256, 0, stream>>>(
      incT, (long)E_ * M_, nfT, (long)D_ * M_, M_, E_, D_, G, nullptr, nullptr, nullptr);
  // 5. S = G @ Wa^T (f32)
  k_gemm<2><<<dim3(256), 256, 0, stream>>>(
      G, (long)E_ * D_, Wab, 0L, D_, E_, D_, nullptr, nullptr, nullptr, S);
  // 6. column softmax stats over e (two-stage)
  k_cstats1<<<dim3(D_ / 64, 4, B_), 256, 0, stream>>>(S, mxp, smp);
  k_cstats2<<<dim3(B_ * D_ / 256), 256, 0, stream>>>(mxp, smp, mx, sm);
  // 7. H = G * softmax_e(S)
  k_H<<<dim3((B_ * E_ * D_) / (256 * 8)), 256, 0, stream>>>(G, S, mx, sm, H);
  // 8. ef = alpha*edge + (1-alpha) * (H @ Wp^T)   [swizzled 1D grid]
  k_gemm<1><<<dim3(256), 256, 0, stream>>>(
      H, (long)E_ * D_, Wpb, 0L, D_, E_, D_, nullptr, edge, alpha, ef);
  // 9-12. edge attention pooling + final projections
  k_z<<<dim3(E_ / 64, B_), 256, 0, stream>>>(ef, attw, z);
  k_zsm<<<dim3(B_), 256, 0, stream>>>(z, az);
  k_pooled<<<dim3(D_ / 64, B_), 256, 0, stream>>>(ef, az, pooled);
  k_out<<<dim3(B_), 256, 0, stream>>>(pooled, projw, projb, fcw, fcb, outp);
}

// Round 4
// 198.052 us; speedup vs baseline: 1.6989x; 1.1763x over previous
//
#include <hip/hip_runtime.h>

#define B_ 8
#define M_ 4096
#define E_ 1024
#define D_ 256
#define C_ 16

typedef unsigned short u16;
typedef unsigned int u32;
typedef float fv4 __attribute__((ext_vector_type(4)));
typedef short bh8 __attribute__((ext_vector_type(8)));

__device__ __forceinline__ float b2f(u16 v) { return __uint_as_float(((unsigned)v) << 16); }
__device__ __forceinline__ u16 f2b(float f) {
  unsigned u = __float_as_uint(f);
  return (u16)((u + 0x7FFFu + ((u >> 16) & 1u)) >> 16);
}
// packs lo -> low 16 bits, hi -> high 16 bits, RNE
__device__ __forceinline__ u32 cvtpk(float lo, float hi) {
  u32 r;
  asm("v_cvt_pk_bf16_f32 %0, %1, %2" : "=v"(r) : "v"(lo), "v"(hi));
  return r;
}

// ---------- convert two f32 arrays to bf16 (Wa, Wp) ----------
__global__ __launch_bounds__(256) void k_cvt2(const float* __restrict__ a, u16* __restrict__ da,
                                              const float* __restrict__ b, u16* __restrict__ db, int n) {
  int i = (blockIdx.x * 256 + threadIdx.x) * 4;
  if (i >= n) return;
  float4 v = *reinterpret_cast<const float4*>(a + i);
  float4 u = *reinterpret_cast<const float4*>(b + i);
  da[i] = f2b(v.x); da[i + 1] = f2b(v.y); da[i + 2] = f2b(v.z); da[i + 3] = f2b(v.w);
  db[i] = f2b(u.x); db[i + 1] = f2b(u.y); db[i + 2] = f2b(u.z); db[i + 3] = f2b(u.w);
}

// ---------- G = inc^T @ nf, fused f32->bf16 convert + transpose-in-LDS ----------
// BM=128 (e), BN=64 (d), BK=64 (m), 256 thr, 4 waves (wave tile 64x32).
// LDS layout As[e][m], Bs[d][m] with 16B-unit XOR swizzle col ^= ((row>>4)&7)<<3
// applied on BOTH the dword writes and the b128 fragment reads.
__global__ __launch_bounds__(256, 1) void k_gemm0(const float* __restrict__ inc,
                                                  const float* __restrict__ nf,
                                                  u16* __restrict__ G) {
  __shared__ u16 As[2][128][72];
  __shared__ u16 Bs[2][64][72];
  int f = blockIdx.x;
  int xcd = f & 7, s = f >> 3;
  int x = s & 3;
  int g = xcd | ((s >> 2) << 3);
  int y = g & 7, b = g >> 3;
  int r0 = y * 128, c0 = x * 64;
  const float* Ab = inc + (long)b * M_ * E_;  // [m][e]
  const float* Bb = nf + (long)b * M_ * D_;   // [m][d]
  int t = threadIdx.x, l = t & 63, w = t >> 6;
  int wr = w >> 1, wc = w & 1;
  int l15 = l & 15, lg = l >> 4;

  int ae = (t & 31) * 4;  // e offset 0..124
  int amp = t >> 5;       // m-pair group 0..7
  int bd = (t & 15) * 4;  // d offset 0..60
  int bmp = t >> 4;       // m-pair group 0..15

  fv4 acc[4][2] = {};
  fv4 pa[8], pb[4];

  auto LOAD = [&](int k0) {
#pragma unroll
    for (int it = 0; it < 4; ++it) {
      int m = k0 + amp * 2 + it * 16;
      pa[it * 2 + 0] = *reinterpret_cast<const fv4*>(Ab + (long)m * E_ + r0 + ae);
      pa[it * 2 + 1] = *reinterpret_cast<const fv4*>(Ab + (long)(m + 1) * E_ + r0 + ae);
    }
#pragma unroll
    for (int it = 0; it < 2; ++it) {
      int m = k0 + bmp * 2 + it * 32;
      pb[it * 2 + 0] = *reinterpret_cast<const fv4*>(Bb + (long)m * D_ + c0 + bd);
      pb[it * 2 + 1] = *reinterpret_cast<const fv4*>(Bb + (long)(m + 1) * D_ + c0 + bd);
    }
  };
  auto WRITE = [&](int cur) {
#pragma unroll
    for (int it = 0; it < 4; ++it) {
      int mc = amp * 2 + it * 16;
#pragma unroll
      for (int j = 0; j < 4; ++j) {
        int e = ae + j;
        int mcw = mc ^ (((e >> 4) & 7) << 3);
        *reinterpret_cast<u32*>(&As[cur][e][mcw]) = cvtpk(pa[it * 2][j], pa[it * 2 + 1][j]);
      }
    }
#pragma unroll
    for (int it = 0; it < 2; ++it) {
      int mc = bmp * 2 + it * 32;
#pragma unroll
      for (int j = 0; j < 4; ++j) {
        int d = bd + j;
        int mcw = mc ^ (((d >> 4) & 7) << 3);
        *reinterpret_cast<u32*>(&Bs[cur][d][mcw]) = cvtpk(pb[it * 2][j], pb[it * 2 + 1][j]);
      }
    }
  };
  auto COMPUTE = [&](int cur) {
#pragma unroll
    for (int kk = 0; kk < 2; ++kk) {
      bh8 af[4], bfr[2];
#pragma unroll
      for (int i = 0; i < 4; ++i) {
        int e = wr * 64 + i * 16 + l15;
        int col = (kk * 32 + lg * 8) ^ (((e >> 4) & 7) << 3);
        af[i] = *reinterpret_cast<const bh8*>(&As[cur][e][col]);
      }
#pragma unroll
      for (int j = 0; j < 2; ++j) {
        int d = wc * 32 + j * 16 + l15;
        int col = (kk * 32 + lg * 8) ^ (((d >> 4) & 7) << 3);
        bfr[j] = *reinterpret_cast<const bh8*>(&Bs[cur][d][col]);
      }
#pragma unroll
      for (int i = 0; i < 4; ++i)
#pragma unroll
        for (int j = 0; j < 2; ++j)
          acc[i][j] = __builtin_amdgcn_mfma_f32_16x16x32_bf16(af[i], bfr[j], acc[i][j], 0, 0, 0);
    }
  };

  LOAD(0);
  WRITE(0);
  __syncthreads();
  int cur = 0;
  for (int kt = 1; kt < M_ / 64; ++kt) {
    LOAD(kt * 64);
    COMPUTE(cur);
    WRITE(cur ^ 1);
    cur ^= 1;
    __syncthreads();
  }
  COMPUTE(cur);

#pragma unroll
  for (int i = 0; i < 4; ++i)
#pragma unroll
    for (int j = 0; j < 2; ++j)
#pragma unroll
      for (int q = 0; q < 4; ++q) {
        int row = r0 + wr * 64 + i * 16 + lg * 4 + q;
        int col = c0 + wc * 32 + j * 16 + l15;
        G[((long)b * E_ + row) * D_ + col] = f2b(acc[i][j][q]);
      }
}

// ---------- shared small-K GEMM: out = A' @ W^T, K=256, BM=128, BN=64 ----------
// MODE 2: A'=G (bf16), write S f32 + per-block column softmax partial stats.
// MODE 1: A'=H=G*exp(S-mx)*sv computed during staging; ef = alpha*edge+(1-alpha)*C.
template <int MODE>
__global__ __launch_bounds__(256, 1) void k_gemmS(
    const u16* __restrict__ A, const u16* __restrict__ Bt,
    const float* __restrict__ Sin, const float* __restrict__ mx, const float* __restrict__ sv,
    float* __restrict__ Sout, float* __restrict__ mxp, float* __restrict__ smp,
    const float* __restrict__ edge, const float* __restrict__ alphap,
    float* __restrict__ outEF) {
  __shared__ u16 As[2][128][72];
  __shared__ u16 Bs[2][64][72];
  __shared__ float sM[2][64], sS[2][64];
  __shared__ float sMx[D_], sSv[D_];
  int f = blockIdx.x;
  int xcd = f & 7, s = f >> 3;
  int x = s & 3;
  int g = xcd | ((s >> 2) << 3);
  int y = g & 7, b = g >> 3;
  int r0 = y * 128, c0 = x * 64;
  const u16* Ab = A + (long)b * E_ * D_;
  int t = threadIdx.x, l = t & 63, w = t >> 6;
  int wr = w >> 1, wc = w & 1;
  int l15 = l & 15, lg = l >> 4;
  int art = t >> 1, akt = (t & 1) * 32;
  int brt = t >> 2, bkt = (t & 3) * 16;

  if (MODE == 1 && t < 64) {
    *reinterpret_cast<fv4*>(&sMx[t * 4]) = *reinterpret_cast<const fv4*>(mx + b * D_ + t * 4);
    *reinterpret_cast<fv4*>(&sSv[t * 4]) = *reinterpret_cast<const fv4*>(sv + b * D_ + t * 4);
  }
  __syncthreads();  // sMx/sSv visible to ALL threads before any WRITE uses them

  fv4 acc[4][2] = {};
  bh8 ga[4], gb[2];
  fv4 sa[8];

  auto LOAD = [&](int k0) {
#pragma unroll
    for (int i = 0; i < 4; ++i)
      ga[i] = *reinterpret_cast<const bh8*>(Ab + (long)(r0 + art) * D_ + k0 + akt + i * 8);
    if (MODE == 1) {
#pragma unroll
      for (int i = 0; i < 8; ++i)
        sa[i] = *reinterpret_cast<const fv4*>(Sin + ((long)b * E_ + r0 + art) * D_ + k0 + akt + i * 4);
    }
#pragma unroll
    for (int i = 0; i < 2; ++i)
      gb[i] = *reinterpret_cast<const bh8*>(Bt + (long)(c0 + brt) * D_ + k0 + bkt + i * 8);
  };
  auto WRITE = [&](int cur, int k0) {
    if (MODE == 2) {
#pragma unroll
      for (int i = 0; i < 4; ++i)
        *reinterpret_cast<bh8*>(&As[cur][art][akt + i * 8]) = ga[i];
    } else {
#pragma unroll
      for (int i = 0; i < 4; ++i) {
        fv4 mA = *reinterpret_cast<const fv4*>(&sMx[k0 + akt + i * 8]);
        fv4 mB = *reinterpret_cast<const fv4*>(&sMx[k0 + akt + i * 8 + 4]);
        fv4 vA = *reinterpret_cast<const fv4*>(&sSv[k0 + akt + i * 8]);
        fv4 vB = *reinterpret_cast<const fv4*>(&sSv[k0 + akt + i * 8 + 4]);
        float h[8];
#pragma unroll
        for (int j = 0; j < 4; ++j) {
          h[j] = b2f((u16)ga[i][j]) * __expf(sa[i * 2][j] - mA[j]) * vA[j];
          h[4 + j] = b2f((u16)ga[i][j + 4]) * __expf(sa[i * 2 + 1][j] - mB[j]) * vB[j];
        }
        union { u32 w4[4]; bh8 v; } hp;
        hp.w4[0] = cvtpk(h[0], h[1]);
        hp.w4[1] = cvtpk(h[2], h[3]);
        hp.w4[2] = cvtpk(h[4], h[5]);
        hp.w4[3] = cvtpk(h[6], h[7]);
        *reinterpret_cast<bh8*>(&As[cur][art][akt + i * 8]) = hp.v;
      }
    }
#pragma unroll
    for (int i = 0; i < 2; ++i)
      *reinterpret_cast<bh8*>(&Bs[cur][brt][bkt + i * 8]) = gb[i];
  };
  auto COMPUTE = [&](int cur) {
#pragma unroll
    for (int kk = 0; kk < 2; ++kk) {
      bh8 af[4], bfr[2];
#pragma unroll
      for (int i = 0; i < 4; ++i)
        af[i] = *reinterpret_cast<const bh8*>(&As[cur][wr * 64 + i * 16 + l15][kk * 32 + lg * 8]);
#pragma unroll
      for (int j = 0; j < 2; ++j)
        bfr[j] = *reinterpret_cast<const bh8*>(&Bs[cur][wc * 32 + j * 16 + l15][kk * 32 + lg * 8]);
#pragma unroll
      for (int i = 0; i < 4; ++i)
#pragma unroll
        for (int j = 0; j < 2; ++j)
          acc[i][j] = __builtin_amdgcn_mfma_f32_16x16x32_bf16(af[i], bfr[j], acc[i][j], 0, 0, 0);
    }
  };

  LOAD(0);
  WRITE(0, 0);
  __syncthreads();
  int cur = 0;
  for (int kt = 1; kt < D_ / 64; ++kt) {
    LOAD(kt * 64);
    COMPUTE(cur);
    WRITE(cur ^ 1, kt * 64);
    cur ^= 1;
    __syncthreads();
  }
  COMPUTE(cur);

  if (MODE == 2) {
    // write S + per-block column stats over this block's 128 e-rows
#pragma unroll
    for (int i = 0; i < 4; ++i)
#pragma unroll
      for (int j = 0; j < 2; ++j)
#pragma unroll
        for (int q = 0; q < 4; ++q) {
          int row = r0 + wr * 64 + i * 16 + lg * 4 + q;
          int col = c0 + wc * 32 + j * 16 + l15;
          Sout[((long)b * E_ + row) * D_ + col] = acc[i][j][q];
        }
#pragma unroll
    for (int j = 0; j < 2; ++j) {
      float m = -3.0e38f;
#pragma unroll
      for (int i = 0; i < 4; ++i)
#pragma unroll
        for (int q = 0; q < 4; ++q) m = fmaxf(m, acc[i][j][q]);
      m = fmaxf(m, __shfl_xor(m, 16));
      m = fmaxf(m, __shfl_xor(m, 32));
      float ssum = 0.f;
#pragma unroll
      for (int i = 0; i < 4; ++i)
#pragma unroll
        for (int q = 0; q < 4; ++q) ssum += __expf(acc[i][j][q] - m);
      ssum += __shfl_xor(ssum, 16);
      ssum += __shfl_xor(ssum, 32);
      if (lg == 0) {
        sM[wr][wc * 32 + j * 16 + l15] = m;
        sS[wr][wc * 32 + j * 16 + l15] = ssum;
      }
    }
    __syncthreads();
    if (t < 64) {
      float m0 = sM[0][t], m1 = sM[1][t];
      float M = fmaxf(m0, m1);
      float ss = sS[0][t] * __expf(m0 - M) + sS[1][t] * __expf(m1 - M);
      int idx = (b * 8 + y) * D_ + c0 + t;
      mxp[idx] = M;
      smp[idx] = ss;
    }
  } else {
    float al = *alphap, oneal = 1.0f - al;
#pragma unroll
    for (int i = 0; i < 4; ++i)
#pragma unroll
      for (int j = 0; j < 2; ++j)
#pragma unroll
        for (int q = 0; q < 4; ++q) {
          int row = r0 + wr * 64 + i * 16 + lg * 4 + q;
          int col = c0 + wc * 32 + j * 16 + l15;
          long idx = ((long)b * E_ + row) * D_ + col;
          outEF[idx] = al * edge[idx] + oneal * acc[i][j][q];
        }
  }
}

// ---------- combine 8 row-segments of column stats; sv = 1/sum ----------
__global__ __launch_bounds__(256) void k_cstats2(const float* __restrict__ mxp, const float* __restrict__ smp,
                                                 float* __restrict__ mx, float* __restrict__ sv) {
  int i = blockIdx.x * 256 + threadIdx.x;  // over B_*D_
  int b = i >> 8, d = i & 255;
  float M = -3.0e38f;
#pragma unroll
  for (int s = 0; s < 8; ++s) M = fmaxf(M, mxp[(b * 8 + s) * D_ + d]);
  float S = 0.f;
#pragma unroll
  for (int s = 0; s < 8; ++s) S += smp[(b * 8 + s) * D_ + d] * __expf(mxp[(b * 8 + s) * D_ + d] - M);
  mx[i] = M;
  sv[i] = 1.0f / S;
}

// ---------- z[b][e] = ef[b][e][:] . attw ----------
__global__ __launch_bounds__(256) void k_z(const float* __restrict__ ef, const float* __restrict__ attw,
                                           float* __restrict__ z) {
  int b = blockIdx.y, e0 = blockIdx.x * 64;
  int w = threadIdx.x >> 6, l = threadIdx.x & 63;
  float4 wv = *reinterpret_cast<const float4*>(attw + l * 4);
  for (int e = e0 + w; e < e0 + 64; e += 4) {
    float4 v = *reinterpret_cast<const float4*>(ef + ((long)b * E_ + e) * D_ + l * 4);
    float p = v.x * wv.x + v.y * wv.y + v.z * wv.z + v.w * wv.w;
#pragma unroll
    for (int off = 32; off; off >>= 1) p += __shfl_down(p, off);
    if (l == 0) z[b * E_ + e] = p;
  }
}

// ---------- softmax over e of z -> az ----------
__global__ __launch_bounds__(256) void k_zsm(const float* __restrict__ z, float* __restrict__ az) {
  int b = blockIdx.x, t = threadIdx.x;
  __shared__ float wred[4];
  float4 v = *reinterpret_cast<const float4*>(z + b * E_ + t * 4);
  float m = fmaxf(fmaxf(v.x, v.y), fmaxf(v.z, v.w));
#pragma unroll
  for (int off = 32; off; off >>= 1) m = fmaxf(m, __shfl_xor(m, off));
  if ((t & 63) == 0) wred[t >> 6] = m;
  __syncthreads();
  m = fmaxf(fmaxf(wred[0], wred[1]), fmaxf(wred[2], wred[3]));
  float e0 = __expf(v.x - m), e1 = __expf(v.y - m), e2 = __expf(v.z - m), e3 = __expf(v.w - m);
  float s = e0 + e1 + e2 + e3;
#pragma unroll
  for (int off = 32; off; off >>= 1) s += __shfl_xor(s, off);
  __syncthreads();
  if ((t & 63) == 0) wred[t >> 6] = s;
  __syncthreads();
  s = wred[0] + wred[1] + wred[2] + wred[3];
  float inv = 1.0f / s;
  float4 o;
  o.x = e0 * inv; o.y = e1 * inv; o.z = e2 * inv; o.w = e3 * inv;
  *reinterpret_cast<float4*>(az + b * E_ + t * 4) = o;
}

// ---------- pooled[b][d] = sum_e az[b][e] * ef[b][e][d] ----------
__global__ __launch_bounds__(256) void k_pooled(const float* __restrict__ ef, const float* __restrict__ az,
                                                float* __restrict__ pooled) {
  int b = blockIdx.y;
  int d = blockIdx.x * 64 + (threadIdx.x & 63);
  int g = threadIdx.x >> 6;
  float a = 0.f;
  for (int e = g; e < E_; e += 4)
    a += az[b * E_ + e] * ef[((long)b * E_ + e) * D_ + d];
  __shared__ float ps[4][64];
  ps[g][threadIdx.x & 63] = a;
  __syncthreads();
  if (threadIdx.x < 64)
    pooled[b * D_ + blockIdx.x * 64 + threadIdx.x] =
        ps[0][threadIdx.x] + ps[1][threadIdx.x] + ps[2][threadIdx.x] + ps[3][threadIdx.x];
}

// ---------- out = pooled@proj^T + b ; logits = out@fc^T + fcb ----------
__global__ __launch_bounds__(256) void k_out(const float* __restrict__ pooled,
                                             const float* __restrict__ projw, const float* __restrict__ projb,
                                             const float* __restrict__ fcw, const float* __restrict__ fcb,
                                             float* __restrict__ outp) {
  int b = blockIdx.x, t = threadIdx.x;
  __shared__ float pl[D_], ov[D_];
  pl[t] = pooled[b * D_ + t];
  __syncthreads();
  float o = projb[t];
  for (int d = 0; d < D_; ++d) o += projw[t * D_ + d] * pl[d];
  ov[t] = o;
  __syncthreads();
  if (t < C_) {
    float lg = fcb[t];
    for (int d = 0; d < D_; ++d) lg += fcw[t * D_ + d] * ov[d];
    outp[b * C_ + t] = lg;
  }
}

extern "C" void kernel_launch(void* const* d_in, const int* in_sizes, int n_in,
                              void* d_out, int out_size, void* d_ws, size_t ws_size,
                              hipStream_t stream) {
  const float* node  = (const float*)d_in[0];
  const float* edge  = (const float*)d_in[1];
  const float* inc   = (const float*)d_in[2];
  const float* Wa    = (const float*)d_in[3];
  const float* Wp    = (const float*)d_in[4];
  const float* alpha = (const float*)d_in[5];
  const float* attw  = (const float*)d_in[6];
  const float* projw = (const float*)d_in[7];
  const float* projb = (const float*)d_in[8];
  const float* fcw   = (const float*)d_in[9];
  const float* fcb   = (const float*)d_in[10];
  float* outp = (float*)d_out;

  char* wsp = (char*)d_ws;
  size_t off = 0;
  auto alloc = [&](size_t bytes) {
    char* p = wsp + off;
    off += (bytes + 255) & ~(size_t)255;
    return (void*)p;
  };
  u16* Wab  = (u16*)alloc((size_t)D_ * D_ * 2);
  u16* Wpb  = (u16*)alloc((size_t)D_ * D_ * 2);
  u16* G    = (u16*)alloc((size_t)B_ * E_ * D_ * 2);
  float* S  = (float*)alloc((size_t)B_ * E_ * D_ * 4);
  float* ef = (float*)alloc((size_t)B_ * E_ * D_ * 4);
  float* mxp = (float*)alloc((size_t)B_ * 8 * D_ * 4);
  float* smp = (float*)alloc((size_t)B_ * 8 * D_ * 4);
  float* mx  = (float*)alloc((size_t)B_ * D_ * 4);
  float* sv  = (float*)alloc((size_t)B_ * D_ * 4);
  float* z   = (float*)alloc((size_t)B_ * E_ * 4);
  float* az  = (float*)alloc((size_t)B_ * E_ * 4);
  float* pooled = (float*)alloc((size_t)B_ * D_ * 4);

  // 1. convert Wa, Wp to bf16
  k_cvt2<<<dim3(D_ * D_ / 1024), 256, 0, stream>>>(Wa, Wab, Wp, Wpb, D_ * D_);
  // 2. G = inc^T @ nf (fused convert+transpose staging, pipelined)
  k_gemm0<<<dim3(256), 256, 0, stream>>>(inc, node, G);
  // 3. S = G @ Wa^T (f32) + partial column softmax stats
  k_gemmS<2><<<dim3(256), 256, 0, stream>>>(G, Wab, nullptr, nullptr, nullptr,
                                            S, mxp, smp, nullptr, nullptr, nullptr);
  // 4. combine stats -> mx, sv(=1/sum)
  k_cstats2<<<dim3(B_ * D_ / 256), 256, 0, stream>>>(mxp, smp, mx, sv);
  // 5. ef = alpha*edge + (1-alpha) * ((G*softmax) @ Wp^T), H fused in staging
  k_gemmS<1><<<dim3(256), 256, 0, stream>>>(G, Wpb, S, mx, sv,
                                            nullptr, nullptr, nullptr, edge, alpha, ef);
  // 6-9. edge attention pooling + final projections
  k_z<<<dim3(E_ / 64, B_), 256, 0, stream>>>(ef, attw, z);
  k_zsm<<<dim3(B_), 256, 0, stream>>>(z, az);
  k_pooled<<<dim3(D_ / 64, B_), 256, 0, stream>>>(ef, az, pooled);
  k_out<<<dim3(B_), 256, 0, stream>>>(pooled, projw, projb, fcw, fcb, outp);
}

// Round 5
// 159.173 us; speedup vs baseline: 2.1139x; 1.2443x over previous
//
#include <hip/hip_runtime.h>

#define B_ 8
#define M_ 4096
#define E_ 1024
#define D_ 256
#define C_ 16

typedef unsigned short u16;
typedef unsigned int u32;
typedef float fv4 __attribute__((ext_vector_type(4)));
typedef short bh8 __attribute__((ext_vector_type(8)));

__device__ __forceinline__ float b2f(u16 v) { return __uint_as_float(((unsigned)v) << 16); }
__device__ __forceinline__ u16 f2b(float f) {
  unsigned u = __float_as_uint(f);
  return (u16)((u + 0x7FFFu + ((u >> 16) & 1u)) >> 16);
}
// packs lo -> low 16 bits, hi -> high 16 bits, RNE
__device__ __forceinline__ u32 cvtpk(float lo, float hi) {
  u32 r;
  asm("v_cvt_pk_bf16_f32 %0, %1, %2" : "=v"(r) : "v"(lo), "v"(hi));
  return r;
}

// ---------- convert two f32 arrays to bf16 (Wa, Wp) ----------
__global__ __launch_bounds__(256) void k_cvt2(const float* __restrict__ a, u16* __restrict__ da,
                                              const float* __restrict__ b, u16* __restrict__ db, int n) {
  int i = (blockIdx.x * 256 + threadIdx.x) * 4;
  if (i >= n) return;
  float4 v = *reinterpret_cast<const float4*>(a + i);
  float4 u = *reinterpret_cast<const float4*>(b + i);
  da[i] = f2b(v.x); da[i + 1] = f2b(v.y); da[i + 2] = f2b(v.z); da[i + 3] = f2b(v.w);
  db[i] = f2b(u.x); db[i + 1] = f2b(u.y); db[i + 2] = f2b(u.z); db[i + 3] = f2b(u.w);
}

// ---------- G = inc^T @ nf, fused convert+transpose, depth-2 prefetch ----------
// BM=64 (e), BN=64 (d), BK=64 (m). Grid 512, 2 blocks/CU, 4 waves (tile 32x32/wave).
// Decode: b = f&7 (batch == XCD), x = (f>>3)&3, y = f>>5.
// LDS As[e][m],Bs[d][m] pad-72, XOR swizzle (16B units) on write+read.
__global__ __launch_bounds__(256, 2) void k_gemm0(const float* __restrict__ inc,
                                                  const float* __restrict__ nf,
                                                  u16* __restrict__ G) {
  __shared__ u16 As[2][64][72];
  __shared__ u16 Bs[2][64][72];
  int f = blockIdx.x;
  int b = f & 7, s = f >> 3;
  int x = s & 3, y = s >> 2;  // x:0..3 (d), y:0..15 (e)
  int r0 = y * 64, c0 = x * 64;
  const float* Ab = inc + (long)b * M_ * E_;  // [m][e]
  const float* Bb = nf + (long)b * M_ * D_;   // [m][d]
  int t = threadIdx.x, l = t & 63, w = t >> 6;
  int wr = w >> 1, wc = w & 1;
  int l15 = l & 15, lg = l >> 4;

  int mrow = t >> 4;        // 0..15 -> owns m rows mrow*4..+3
  int ecol = (t & 15) * 4;  // e/d offset 0..60

  fv4 acc[2][2] = {};
  fv4 pa0[4], pb0[4], pa1[4], pb1[4];  // two named prefetch sets (rule #20)

  auto LOAD = [&](int k0, fv4 (&pa)[4], fv4 (&pb)[4]) {
    const float* ap = Ab + (long)(k0 + mrow * 4) * E_ + r0 + ecol;
    const float* bp = Bb + (long)(k0 + mrow * 4) * D_ + c0 + ecol;
#pragma unroll
    for (int r = 0; r < 4; ++r) {
      pa[r] = *reinterpret_cast<const fv4*>(ap + (long)r * E_);
      pb[r] = *reinterpret_cast<const fv4*>(bp + (long)r * D_);
    }
  };
  auto WRITE = [&](const fv4 (&pa)[4], const fv4 (&pb)[4], int buf) {
    int mc = mrow * 4;
#pragma unroll
    for (int j = 0; j < 4; ++j) {
      int e = ecol + j;
      int mcw = mc ^ (((e >> 4) & 7) << 3);
      uint2 va, vb;
      va.x = cvtpk(pa[0][j], pa[1][j]);
      va.y = cvtpk(pa[2][j], pa[3][j]);
      vb.x = cvtpk(pb[0][j], pb[1][j]);
      vb.y = cvtpk(pb[2][j], pb[3][j]);
      *reinterpret_cast<uint2*>(&As[buf][e][mcw]) = va;
      *reinterpret_cast<uint2*>(&Bs[buf][e][mcw]) = vb;
    }
  };
  auto COMPUTE = [&](int buf) {
#pragma unroll
    for (int kk = 0; kk < 2; ++kk) {
      bh8 af[2], bf[2];
#pragma unroll
      for (int i = 0; i < 2; ++i) {
        int e = wr * 32 + i * 16 + l15;
        int col = (kk * 32 + lg * 8) ^ (((e >> 4) & 7) << 3);
        af[i] = *reinterpret_cast<const bh8*>(&As[buf][e][col]);
      }
#pragma unroll
      for (int j = 0; j < 2; ++j) {
        int d = wc * 32 + j * 16 + l15;
        int col = (kk * 32 + lg * 8) ^ (((d >> 4) & 7) << 3);
        bf[j] = *reinterpret_cast<const bh8*>(&Bs[buf][d][col]);
      }
#pragma unroll
      for (int i = 0; i < 2; ++i)
#pragma unroll
        for (int j = 0; j < 2; ++j)
          acc[i][j] = __builtin_amdgcn_mfma_f32_16x16x32_bf16(af[i], bf[j], acc[i][j], 0, 0, 0);
    }
  };

  const int NT = M_ / 64;  // 64, even
  LOAD(0, pa0, pb0);
  LOAD(64, pa1, pb1);
  WRITE(pa0, pb0, 0);
  __syncthreads();
  for (int kt = 0; kt < NT; kt += 2) {
    // even: compute tile kt (buf0); write tile kt+1 (set1->buf1); prefetch kt+2 -> set0
    if (kt + 2 < NT) LOAD((kt + 2) * 64, pa0, pb0);
    COMPUTE(0);
    WRITE(pa1, pb1, 1);
    __syncthreads();
    // odd: compute tile kt+1 (buf1); write tile kt+2 (set0->buf0); prefetch kt+3 -> set1
    if (kt + 3 < NT) LOAD((kt + 3) * 64, pa1, pb1);
    COMPUTE(1);
    if (kt + 2 < NT) WRITE(pa0, pb0, 0);
    __syncthreads();
  }

#pragma unroll
  for (int i = 0; i < 2; ++i)
#pragma unroll
    for (int j = 0; j < 2; ++j)
#pragma unroll
      for (int q = 0; q < 4; ++q) {
        int row = r0 + wr * 32 + i * 16 + lg * 4 + q;
        int col = c0 + wc * 32 + j * 16 + l15;
        G[((long)b * E_ + row) * D_ + col] = f2b(acc[i][j][q]);
      }
}

// ---------- small-K GEMM: out = A' @ W^T, K=256 in 4 chunks of 64, depth-2 prefetch ----------
// BM=64, BN=64, grid 512, 2 blocks/CU.
// MODE 2: A'=G bf16, write S f32 + per-block column softmax partial stats (seg y of 16).
// MODE 1: A'=H=G*exp(S-mx)*sv computed during staging; ef = alpha*edge+(1-alpha)*C.
template <int MODE>
__global__ __launch_bounds__(256, 2) void k_gemmS(
    const u16* __restrict__ A, const u16* __restrict__ Bt,
    const float* __restrict__ Sin, const float* __restrict__ mx, const float* __restrict__ sv,
    float* __restrict__ Sout, float* __restrict__ mxp, float* __restrict__ smp,
    const float* __restrict__ edge, const float* __restrict__ alphap,
    float* __restrict__ outEF) {
  __shared__ u16 As[2][64][72];
  __shared__ u16 Bs[2][64][72];
  __shared__ float sM[2][64], sS[2][64];
  __shared__ float sMx[D_], sSv[D_];
  int f = blockIdx.x;
  int b = f & 7, s = f >> 3;
  int x = s & 3, y = s >> 2;
  int r0 = y * 64, c0 = x * 64;
  const u16* Ab = A + (long)b * E_ * D_;
  int t = threadIdx.x, l = t & 63, w = t >> 6;
  int wr = w >> 1, wc = w & 1;
  int l15 = l & 15, lg = l >> 4;
  int rA = t >> 2, kA = (t & 3) * 16;  // row 0..63, k-offset 0..48

  if (MODE == 1 && t < 64) {
    *reinterpret_cast<fv4*>(&sMx[t * 4]) = *reinterpret_cast<const fv4*>(mx + b * D_ + t * 4);
    *reinterpret_cast<fv4*>(&sSv[t * 4]) = *reinterpret_cast<const fv4*>(sv + b * D_ + t * 4);
  }
  __syncthreads();

  fv4 acc[2][2] = {};
  bh8 ga0[2], gb0[2], ga1[2], gb1[2];
  fv4 sa0[4], sa1[4];

  auto LOAD = [&](int k0, bh8 (&ga)[2], bh8 (&gb)[2], fv4 (&sa)[4]) {
    const u16* ap = Ab + (long)(r0 + rA) * D_ + k0 + kA;
    const u16* bp = Bt + (long)(c0 + rA) * D_ + k0 + kA;
    ga[0] = *reinterpret_cast<const bh8*>(ap);
    ga[1] = *reinterpret_cast<const bh8*>(ap + 8);
    gb[0] = *reinterpret_cast<const bh8*>(bp);
    gb[1] = *reinterpret_cast<const bh8*>(bp + 8);
    if (MODE == 1) {
      const float* sp = Sin + ((long)b * E_ + r0 + rA) * D_ + k0 + kA;
#pragma unroll
      for (int i = 0; i < 4; ++i) sa[i] = *reinterpret_cast<const fv4*>(sp + i * 4);
    }
  };
  auto WRITE = [&](const bh8 (&ga)[2], const bh8 (&gb)[2], const fv4 (&sa)[4], int buf, int k0) {
    if (MODE == 2) {
      *reinterpret_cast<bh8*>(&As[buf][rA][kA]) = ga[0];
      *reinterpret_cast<bh8*>(&As[buf][rA][kA + 8]) = ga[1];
    } else {
#pragma unroll
      for (int h = 0; h < 2; ++h) {
        fv4 mA = *reinterpret_cast<const fv4*>(&sMx[k0 + kA + h * 8]);
        fv4 mB = *reinterpret_cast<const fv4*>(&sMx[k0 + kA + h * 8 + 4]);
        fv4 vA = *reinterpret_cast<const fv4*>(&sSv[k0 + kA + h * 8]);
        fv4 vB = *reinterpret_cast<const fv4*>(&sSv[k0 + kA + h * 8 + 4]);
        float hf[8];
#pragma unroll
        for (int j = 0; j < 4; ++j) {
          hf[j]     = b2f((u16)ga[h][j])     * __expf(sa[h * 2][j]     - mA[j]) * vA[j];
          hf[4 + j] = b2f((u16)ga[h][j + 4]) * __expf(sa[h * 2 + 1][j] - mB[j]) * vB[j];
        }
        union { u32 w4[4]; bh8 v; } hp;
        hp.w4[0] = cvtpk(hf[0], hf[1]);
        hp.w4[1] = cvtpk(hf[2], hf[3]);
        hp.w4[2] = cvtpk(hf[4], hf[5]);
        hp.w4[3] = cvtpk(hf[6], hf[7]);
        *reinterpret_cast<bh8*>(&As[buf][rA][kA + h * 8]) = hp.v;
      }
    }
    *reinterpret_cast<bh8*>(&Bs[buf][rA][kA]) = gb[0];
    *reinterpret_cast<bh8*>(&Bs[buf][rA][kA + 8]) = gb[1];
  };
  auto COMPUTE = [&](int buf) {
#pragma unroll
    for (int kk = 0; kk < 2; ++kk) {
      bh8 af[2], bf[2];
#pragma unroll
      for (int i = 0; i < 2; ++i)
        af[i] = *reinterpret_cast<const bh8*>(&As[buf][wr * 32 + i * 16 + l15][kk * 32 + lg * 8]);
#pragma unroll
      for (int j = 0; j < 2; ++j)
        bf[j] = *reinterpret_cast<const bh8*>(&Bs[buf][wc * 32 + j * 16 + l15][kk * 32 + lg * 8]);
#pragma unroll
      for (int i = 0; i < 2; ++i)
#pragma unroll
        for (int j = 0; j < 2; ++j)
          acc[i][j] = __builtin_amdgcn_mfma_f32_16x16x32_bf16(af[i], bf[j], acc[i][j], 0, 0, 0);
    }
  };

  const int NT = D_ / 64;  // 4, even
  LOAD(0, ga0, gb0, sa0);
  LOAD(64, ga1, gb1, sa1);
  WRITE(ga0, gb0, sa0, 0, 0);
  __syncthreads();
  for (int kt = 0; kt < NT; kt += 2) {
    if (kt + 2 < NT) LOAD((kt + 2) * 64, ga0, gb0, sa0);
    COMPUTE(0);
    WRITE(ga1, gb1, sa1, 1, (kt + 1) * 64);
    __syncthreads();
    if (kt + 3 < NT) LOAD((kt + 3) * 64, ga1, gb1, sa1);
    COMPUTE(1);
    if (kt + 2 < NT) WRITE(ga0, gb0, sa0, 0, (kt + 2) * 64);
    __syncthreads();
  }

  if (MODE == 2) {
#pragma unroll
    for (int i = 0; i < 2; ++i)
#pragma unroll
      for (int j = 0; j < 2; ++j)
#pragma unroll
        for (int q = 0; q < 4; ++q) {
          int row = r0 + wr * 32 + i * 16 + lg * 4 + q;
          int col = c0 + wc * 32 + j * 16 + l15;
          Sout[((long)b * E_ + row) * D_ + col] = acc[i][j][q];
        }
#pragma unroll
    for (int j = 0; j < 2; ++j) {
      float m = -3.0e38f;
#pragma unroll
      for (int i = 0; i < 2; ++i)
#pragma unroll
        for (int q = 0; q < 4; ++q) m = fmaxf(m, acc[i][j][q]);
      m = fmaxf(m, __shfl_xor(m, 16));
      m = fmaxf(m, __shfl_xor(m, 32));
      float ssum = 0.f;
#pragma unroll
      for (int i = 0; i < 2; ++i)
#pragma unroll
        for (int q = 0; q < 4; ++q) ssum += __expf(acc[i][j][q] - m);
      ssum += __shfl_xor(ssum, 16);
      ssum += __shfl_xor(ssum, 32);
      if (lg == 0) {
        sM[wr][wc * 32 + j * 16 + l15] = m;
        sS[wr][wc * 32 + j * 16 + l15] = ssum;
      }
    }
    __syncthreads();
    if (t < 64) {
      float m0 = sM[0][t], m1 = sM[1][t];
      float M = fmaxf(m0, m1);
      float ss = sS[0][t] * __expf(m0 - M) + sS[1][t] * __expf(m1 - M);
      int idx = (b * 16 + y) * D_ + c0 + t;
      mxp[idx] = M;
      smp[idx] = ss;
    }
  } else {
    float al = *alphap, oneal = 1.0f - al;
#pragma unroll
    for (int i = 0; i < 2; ++i)
#pragma unroll
      for (int j = 0; j < 2; ++j)
#pragma unroll
        for (int q = 0; q < 4; ++q) {
          int row = r0 + wr * 32 + i * 16 + lg * 4 + q;
          int col = c0 + wc * 32 + j * 16 + l15;
          long idx = ((long)b * E_ + row) * D_ + col;
          outEF[idx] = al * edge[idx] + oneal * acc[i][j][q];
        }
  }
}

// ---------- combine 16 row-segments of column stats; sv = 1/sum ----------
__global__ __launch_bounds__(256) void k_cstats2(const float* __restrict__ mxp, const float* __restrict__ smp,
                                                 float* __restrict__ mx, float* __restrict__ sv) {
  int i = blockIdx.x * 256 + threadIdx.x;  // over B_*D_
  int b = i >> 8, d = i & 255;
  float M = -3.0e38f;
#pragma unroll
  for (int s = 0; s < 16; ++s) M = fmaxf(M, mxp[(b * 16 + s) * D_ + d]);
  float S = 0.f;
#pragma unroll
  for (int s = 0; s < 16; ++s) S += smp[(b * 16 + s) * D_ + d] * __expf(mxp[(b * 16 + s) * D_ + d] - M);
  mx[i] = M;
  sv[i] = 1.0f / S;
}

// ---------- z[b][e] = ef[b][e][:] . attw ----------
__global__ __launch_bounds__(256) void k_z(const float* __restrict__ ef, const float* __restrict__ attw,
                                           float* __restrict__ z) {
  int b = blockIdx.y, e0 = blockIdx.x * 64;
  int w = threadIdx.x >> 6, l = threadIdx.x & 63;
  float4 wv = *reinterpret_cast<const float4*>(attw + l * 4);
  for (int e = e0 + w; e < e0 + 64; e += 4) {
    float4 v = *reinterpret_cast<const float4*>(ef + ((long)b * E_ + e) * D_ + l * 4);
    float p = v.x * wv.x + v.y * wv.y + v.z * wv.z + v.w * wv.w;
#pragma unroll
    for (int off = 32; off; off >>= 1) p += __shfl_down(p, off);
    if (l == 0) z[b * E_ + e] = p;
  }
}

// ---------- softmax over e of z -> az ----------
__global__ __launch_bounds__(256) void k_zsm(const float* __restrict__ z, float* __restrict__ az) {
  int b = blockIdx.x, t = threadIdx.x;
  __shared__ float wred[4];
  float4 v = *reinterpret_cast<const float4*>(z + b * E_ + t * 4);
  float m = fmaxf(fmaxf(v.x, v.y), fmaxf(v.z, v.w));
#pragma unroll
  for (int off = 32; off; off >>= 1) m = fmaxf(m, __shfl_xor(m, off));
  if ((t & 63) == 0) wred[t >> 6] = m;
  __syncthreads();
  m = fmaxf(fmaxf(wred[0], wred[1]), fmaxf(wred[2], wred[3]));
  float e0 = __expf(v.x - m), e1 = __expf(v.y - m), e2 = __expf(v.z - m), e3 = __expf(v.w - m);
  float s = e0 + e1 + e2 + e3;
#pragma unroll
  for (int off = 32; off; off >>= 1) s += __shfl_xor(s, off);
  __syncthreads();
  if ((t & 63) == 0) wred[t >> 6] = s;
  __syncthreads();
  s = wred[0] + wred[1] + wred[2] + wred[3];
  float inv = 1.0f / s;
  float4 o;
  o.x = e0 * inv; o.y = e1 * inv; o.z = e2 * inv; o.w = e3 * inv;
  *reinterpret_cast<float4*>(az + b * E_ + t * 4) = o;
}

// ---------- pooled[b][d] = sum_e az[b][e] * ef[b][e][d] ----------
__global__ __launch_bounds__(256) void k_pooled(const float* __restrict__ ef, const float* __restrict__ az,
                                                float* __restrict__ pooled) {
  int b = blockIdx.y;
  int d = blockIdx.x * 64 + (threadIdx.x & 63);
  int g = threadIdx.x >> 6;
  float a = 0.f;
  for (int e = g; e < E_; e += 4)
    a += az[b * E_ + e] * ef[((long)b * E_ + e) * D_ + d];
  __shared__ float ps[4][64];
  ps[g][threadIdx.x & 63] = a;
  __syncthreads();
  if (threadIdx.x < 64)
    pooled[b * D_ + blockIdx.x * 64 + threadIdx.x] =
        ps[0][threadIdx.x] + ps[1][threadIdx.x] + ps[2][threadIdx.x] + ps[3][threadIdx.x];
}

// ---------- out = pooled@proj^T + b ; logits = out@fc^T + fcb ----------
__global__ __launch_bounds__(256) void k_out(const float* __restrict__ pooled,
                                             const float* __restrict__ projw, const float* __restrict__ projb,
                                             const float* __restrict__ fcw, const float* __restrict__ fcb,
                                             float* __restrict__ outp) {
  int b = blockIdx.x, t = threadIdx.x;
  __shared__ float pl[D_], ov[D_];
  pl[t] = pooled[b * D_ + t];
  __syncthreads();
  float o = projb[t];
  for (int d = 0; d < D_; ++d) o += projw[t * D_ + d] * pl[d];
  ov[t] = o;
  __syncthreads();
  if (t < C_) {
    float lg = fcb[t];
    for (int d = 0; d < D_; ++d) lg += fcw[t * D_ + d] * ov[d];
    outp[b * C_ + t] = lg;
  }
}

extern "C" void kernel_launch(void* const* d_in, const int* in_sizes, int n_in,
                              void* d_out, int out_size, void* d_ws, size_t ws_size,
                              hipStream_t stream) {
  const float* node  = (const float*)d_in[0];
  const float* edge  = (const float*)d_in[1];
  const float* inc   = (const float*)d_in[2];
  const float* Wa    = (const float*)d_in[3];
  const float* Wp    = (const float*)d_in[4];
  const float* alpha = (const float*)d_in[5];
  const float* attw  = (const float*)d_in[6];
  const float* projw = (const float*)d_in[7];
  const float* projb = (const float*)d_in[8];
  const float* fcw   = (const float*)d_in[9];
  const float* fcb   = (const float*)d_in[10];
  float* outp = (float*)d_out;

  char* wsp = (char*)d_ws;
  size_t off = 0;
  auto alloc = [&](size_t bytes) {
    char* p = wsp + off;
    off += (bytes + 255) & ~(size_t)255;
    return (void*)p;
  };
  u16* Wab  = (u16*)alloc((size_t)D_ * D_ * 2);
  u16* Wpb  = (u16*)alloc((size_t)D_ * D_ * 2);
  u16* G    = (u16*)alloc((size_t)B_ * E_ * D_ * 2);
  float* S  = (float*)alloc((size_t)B_ * E_ * D_ * 4);
  float* ef = (float*)alloc((size_t)B_ * E_ * D_ * 4);
  float* mxp = (float*)alloc((size_t)B_ * 16 * D_ * 4);
  float* smp = (float*)alloc((size_t)B_ * 16 * D_ * 4);
  float* mx  = (float*)alloc((size_t)B_ * D_ * 4);
  float* sv  = (float*)alloc((size_t)B_ * D_ * 4);
  float* z   = (float*)alloc((size_t)B_ * E_ * 4);
  float* az  = (float*)alloc((size_t)B_ * E_ * 4);
  float* pooled = (float*)alloc((size_t)B_ * D_ * 4);

  // 1. convert Wa, Wp to bf16
  k_cvt2<<<dim3(D_ * D_ / 1024), 256, 0, stream>>>(Wa, Wab, Wp, Wpb, D_ * D_);
  // 2. G = inc^T @ nf (fused convert+transpose staging, depth-2 pipeline)
  k_gemm0<<<dim3(512), 256, 0, stream>>>(inc, node, G);
  // 3. S = G @ Wa^T (f32) + partial column softmax stats (16 segs)
  k_gemmS<2><<<dim3(512), 256, 0, stream>>>(G, Wab, nullptr, nullptr, nullptr,
                                            S, mxp, smp, nullptr, nullptr, nullptr);
  // 4. combine stats -> mx, sv(=1/sum)
  k_cstats2<<<dim3(B_ * D_ / 256), 256, 0, stream>>>(mxp, smp, mx, sv);
  // 5. ef = alpha*edge + (1-alpha) * ((G*softmax) @ Wp^T), H fused in staging
  k_gemmS<1><<<dim3(512), 256, 0, stream>>>(G, Wpb, S, mx, sv,
                                            nullptr, nullptr, nullptr, edge, alpha, ef);
  // 6-9. edge attention pooling + final projections
  k_z<<<dim3(E_ / 64, B_), 256, 0, stream>>>(ef, attw, z);
  k_zsm<<<dim3(B_), 256, 0, stream>>>(z, az);
  k_pooled<<<dim3(D_ / 64, B_), 256, 0, stream>>>(ef, az, pooled);
  k_out<<<dim3(B_), 256, 0, stream>>>(pooled, projw, projb, fcw, fcb, outp);
}

// Round 6
// 158.518 us; speedup vs baseline: 2.1226x; 1.0041x over previous
//
#include <hip/hip_runtime.h>

#define B_ 8
#define M_ 4096
#define E_ 1024
#define D_ 256
#define C_ 16

typedef unsigned short u16;
typedef unsigned int u32;
typedef float fv4 __attribute__((ext_vector_type(4)));
typedef short bh8 __attribute__((ext_vector_type(8)));

__device__ __forceinline__ float b2f(u16 v) { return __uint_as_float(((unsigned)v) << 16); }
__device__ __forceinline__ u16 f2b(float f) {
  unsigned u = __float_as_uint(f);
  return (u16)((u + 0x7FFFu + ((u >> 16) & 1u)) >> 16);
}
// packs lo -> low 16 bits, hi -> high 16 bits, RNE
__device__ __forceinline__ u32 cvtpk(float lo, float hi) {
  u32 r;
  asm("v_cvt_pk_bf16_f32 %0, %1, %2" : "=v"(r) : "v"(lo), "v"(hi));
  return r;
}
// per-row granule swizzle (16B granules, 8 per 64-u16 row segment)
__device__ __forceinline__ int xf(int r) { return ((r >> 2) ^ (r >> 5)) & 7; }

// ---------- convert two f32 arrays to bf16 (Wa, Wp) ----------
__global__ __launch_bounds__(256) void k_cvt2(const float* __restrict__ a, u16* __restrict__ da,
                                              const float* __restrict__ b, u16* __restrict__ db, int n) {
  int i = (blockIdx.x * 256 + threadIdx.x) * 4;
  if (i >= n) return;
  float4 v = *reinterpret_cast<const float4*>(a + i);
  float4 u = *reinterpret_cast<const float4*>(b + i);
  da[i] = f2b(v.x); da[i + 1] = f2b(v.y); da[i + 2] = f2b(v.z); da[i + 3] = f2b(v.w);
  db[i] = f2b(u.x); db[i + 1] = f2b(u.y); db[i + 2] = f2b(u.z); db[i + 3] = f2b(u.w);
}

// ---------- split-K partial GEMM: P[kc] += inc^T @ nf over m-chunk ----------
// BM=128(e) x BN=256(d, full) x BK=64, split-K=4 (1024 m each).
// 512 threads = 8 waves (2x4 of 64x64 tiles). Grid 256, b=f&7 (batch per XCD).
__global__ __launch_bounds__(512, 2) void k_gemm0(const float* __restrict__ inc,
                                                  const float* __restrict__ nf,
                                                  float* __restrict__ P) {
  __shared__ u16 As[2][128][72];
  __shared__ u16 Bs[2][256][72];
  int f = blockIdx.x;
  int b = f & 7, s = f >> 3;
  int eb = s & 7, kc = s >> 3;
  int r0 = eb * 128;
  const float* Ab = inc + (long)b * M_ * E_ + (long)kc * 1024 * E_;  // [m][e]
  const float* Bb = nf + (long)b * M_ * D_ + (long)kc * 1024 * D_;   // [m][d]
  int t = threadIdx.x, l = t & 63, w = t >> 6;
  int l15 = l & 15, lg = l >> 4;
  int we = (w >> 2) * 64, wd = (w & 3) * 64;

  // staging assignment
  int am = (t >> 5) * 4;        // A m-rows am..am+3
  int ae = (t & 31) * 4;        // A e-cols ae..ae+3
  int bm = (t >> 6) * 8;        // B m-rows bm..bm+7
  int bd = (t & 63) * 4;        // B d-cols bd..bd+3

  fv4 acc[4][4] = {};
  fv4 pa[4], pb[8];

  auto LOAD = [&](int k0) {
#pragma unroll
    for (int r = 0; r < 4; ++r)
      pa[r] = *reinterpret_cast<const fv4*>(Ab + (long)(k0 + am + r) * E_ + r0 + ae);
#pragma unroll
    for (int r = 0; r < 8; ++r)
      pb[r] = *reinterpret_cast<const fv4*>(Bb + (long)(k0 + bm + r) * D_ + bd);
  };
  auto WRITE = [&](int buf) {
    int ga = am >> 3, offa = am & 7;
#pragma unroll
    for (int j = 0; j < 4; ++j) {
      int e = ae + j;
      int colw = ((ga ^ xf(e)) << 3) + offa;
      uint2 va;
      va.x = cvtpk(pa[0][j], pa[1][j]);
      va.y = cvtpk(pa[2][j], pa[3][j]);
      *reinterpret_cast<uint2*>(&As[buf][e][colw]) = va;
    }
    int gb = bm >> 3;
#pragma unroll
    for (int j = 0; j < 4; ++j) {
      int d = bd + j;
      int colw = (gb ^ xf(d)) << 3;
      uint4 vb;
      vb.x = cvtpk(pb[0][j], pb[1][j]);
      vb.y = cvtpk(pb[2][j], pb[3][j]);
      vb.z = cvtpk(pb[4][j], pb[5][j]);
      vb.w = cvtpk(pb[6][j], pb[7][j]);
      *reinterpret_cast<uint4*>(&Bs[buf][d][colw]) = vb;
    }
  };
  auto COMPUTE = [&](int buf) {
#pragma unroll
    for (int kk = 0; kk < 2; ++kk) {
      int gc = kk * 4 + lg;
      bh8 af[4], bf[4];
#pragma unroll
      for (int i = 0; i < 4; ++i) {
        int e = we + i * 16 + l15;
        af[i] = *reinterpret_cast<const bh8*>(&As[buf][e][(gc ^ xf(e)) << 3]);
      }
#pragma unroll
      for (int jj = 0; jj < 4; ++jj) {
        int d = wd + jj * 16 + l15;
        bf[jj] = *reinterpret_cast<const bh8*>(&Bs[buf][d][(gc ^ xf(d)) << 3]);
      }
#pragma unroll
      for (int i = 0; i < 4; ++i)
#pragma unroll
        for (int jj = 0; jj < 4; ++jj)
          acc[i][jj] = __builtin_amdgcn_mfma_f32_16x16x32_bf16(af[i], bf[jj], acc[i][jj], 0, 0, 0);
    }
  };

  LOAD(0);
  WRITE(0);
  __syncthreads();
  const int NIT = 16;  // 1024 / 64
  for (int kt = 0; kt < NIT; ++kt) {
    if (kt < NIT - 1) LOAD((kt + 1) * 64);
    COMPUTE(kt & 1);
    if (kt < NIT - 1) {
      WRITE((kt + 1) & 1);
      __syncthreads();
    }
  }

  float* Pp = P + ((long)(kc * B_ + b) * E_ + r0) * D_;
#pragma unroll
  for (int i = 0; i < 4; ++i)
#pragma unroll
    for (int jj = 0; jj < 4; ++jj)
#pragma unroll
      for (int q = 0; q < 4; ++q) {
        int row = we + i * 16 + lg * 4 + q;
        int col = wd + jj * 16 + l15;
        Pp[(long)row * D_ + col] = acc[i][jj][q];
      }
}

// ---------- reduce 4 split-K partials -> G bf16 ----------
__global__ __launch_bounds__(256) void k_red(const float* __restrict__ P, u16* __restrict__ G) {
  const long CS = (long)B_ * E_ * D_;
  long i = ((long)blockIdx.x * 256 + threadIdx.x) * 4;
  fv4 s0 = *reinterpret_cast<const fv4*>(P + i);
  fv4 s1 = *reinterpret_cast<const fv4*>(P + CS + i);
  fv4 s2 = *reinterpret_cast<const fv4*>(P + 2 * CS + i);
  fv4 s3 = *reinterpret_cast<const fv4*>(P + 3 * CS + i);
  fv4 sum = (s0 + s1) + (s2 + s3);
  uint2 o;
  o.x = cvtpk(sum[0], sum[1]);
  o.y = cvtpk(sum[2], sum[3]);
  *reinterpret_cast<uint2*>(G + i) = o;
}

// ---------- small-K GEMM: out = A' @ W^T, K=256 in 4 chunks of 64, depth-2 prefetch ----------
// BM=64, BN=64, grid 512, 2 blocks/CU.
// MODE 2: A'=G bf16, write S f32 + per-block column softmax partial stats (seg y of 16).
// MODE 1: A'=H=G*exp(S-mx)*sv computed during staging; ef = alpha*edge+(1-alpha)*C.
template <int MODE>
__global__ __launch_bounds__(256, 2) void k_gemmS(
    const u16* __restrict__ A, const u16* __restrict__ Bt,
    const float* __restrict__ Sin, const float* __restrict__ mx, const float* __restrict__ sv,
    float* __restrict__ Sout, float* __restrict__ mxp, float* __restrict__ smp,
    const float* __restrict__ edge, const float* __restrict__ alphap,
    float* __restrict__ outEF) {
  __shared__ u16 As[2][64][72];
  __shared__ u16 Bs[2][64][72];
  __shared__ float sM[2][64], sS[2][64];
  __shared__ float sMx[D_], sSv[D_];
  int f = blockIdx.x;
  int b = f & 7, s = f >> 3;
  int x = s & 3, y = s >> 2;
  int r0 = y * 64, c0 = x * 64;
  const u16* Ab = A + (long)b * E_ * D_;
  int t = threadIdx.x, l = t & 63, w = t >> 6;
  int wr = w >> 1, wc = w & 1;
  int l15 = l & 15, lg = l >> 4;
  int rA = t >> 2, kA = (t & 3) * 16;  // row 0..63, k-offset 0..48

  if (MODE == 1 && t < 64) {
    *reinterpret_cast<fv4*>(&sMx[t * 4]) = *reinterpret_cast<const fv4*>(mx + b * D_ + t * 4);
    *reinterpret_cast<fv4*>(&sSv[t * 4]) = *reinterpret_cast<const fv4*>(sv + b * D_ + t * 4);
  }
  __syncthreads();

  fv4 acc[2][2] = {};
  bh8 ga0[2], gb0[2], ga1[2], gb1[2];
  fv4 sa0[4], sa1[4];

  auto LOAD = [&](int k0, bh8 (&ga)[2], bh8 (&gb)[2], fv4 (&sa)[4]) {
    const u16* ap = Ab + (long)(r0 + rA) * D_ + k0 + kA;
    const u16* bp = Bt + (long)(c0 + rA) * D_ + k0 + kA;
    ga[0] = *reinterpret_cast<const bh8*>(ap);
    ga[1] = *reinterpret_cast<const bh8*>(ap + 8);
    gb[0] = *reinterpret_cast<const bh8*>(bp);
    gb[1] = *reinterpret_cast<const bh8*>(bp + 8);
    if (MODE == 1) {
      const float* sp = Sin + ((long)b * E_ + r0 + rA) * D_ + k0 + kA;
#pragma unroll
      for (int i = 0; i < 4; ++i) sa[i] = *reinterpret_cast<const fv4*>(sp + i * 4);
    }
  };
  auto WRITE = [&](const bh8 (&ga)[2], const bh8 (&gb)[2], const fv4 (&sa)[4], int buf, int k0) {
    if (MODE == 2) {
      *reinterpret_cast<bh8*>(&As[buf][rA][kA]) = ga[0];
      *reinterpret_cast<bh8*>(&As[buf][rA][kA + 8]) = ga[1];
    } else {
#pragma unroll
      for (int h = 0; h < 2; ++h) {
        fv4 mA = *reinterpret_cast<const fv4*>(&sMx[k0 + kA + h * 8]);
        fv4 mB = *reinterpret_cast<const fv4*>(&sMx[k0 + kA + h * 8 + 4]);
        fv4 vA = *reinterpret_cast<const fv4*>(&sSv[k0 + kA + h * 8]);
        fv4 vB = *reinterpret_cast<const fv4*>(&sSv[k0 + kA + h * 8 + 4]);
        float hf[8];
#pragma unroll
        for (int j = 0; j < 4; ++j) {
          hf[j]     = b2f((u16)ga[h][j])     * __expf(sa[h * 2][j]     - mA[j]) * vA[j];
          hf[4 + j] = b2f((u16)ga[h][j + 4]) * __expf(sa[h * 2 + 1][j] - mB[j]) * vB[j];
        }
        union { u32 w4[4]; bh8 v; } hp;
        hp.w4[0] = cvtpk(hf[0], hf[1]);
        hp.w4[1] = cvtpk(hf[2], hf[3]);
        hp.w4[2] = cvtpk(hf[4], hf[5]);
        hp.w4[3] = cvtpk(hf[6], hf[7]);
        *reinterpret_cast<bh8*>(&As[buf][rA][kA + h * 8]) = hp.v;
      }
    }
    *reinterpret_cast<bh8*>(&Bs[buf][rA][kA]) = gb[0];
    *reinterpret_cast<bh8*>(&Bs[buf][rA][kA + 8]) = gb[1];
  };
  auto COMPUTE = [&](int buf) {
#pragma unroll
    for (int kk = 0; kk < 2; ++kk) {
      bh8 af[2], bf[2];
#pragma unroll
      for (int i = 0; i < 2; ++i)
        af[i] = *reinterpret_cast<const bh8*>(&As[buf][wr * 32 + i * 16 + l15][kk * 32 + lg * 8]);
#pragma unroll
      for (int j = 0; j < 2; ++j)
        bf[j] = *reinterpret_cast<const bh8*>(&Bs[buf][wc * 32 + j * 16 + l15][kk * 32 + lg * 8]);
#pragma unroll
      for (int i = 0; i < 2; ++i)
#pragma unroll
        for (int j = 0; j < 2; ++j)
          acc[i][j] = __builtin_amdgcn_mfma_f32_16x16x32_bf16(af[i], bf[j], acc[i][j], 0, 0, 0);
    }
  };

  const int NT = D_ / 64;  // 4, even
  LOAD(0, ga0, gb0, sa0);
  LOAD(64, ga1, gb1, sa1);
  WRITE(ga0, gb0, sa0, 0, 0);
  __syncthreads();
  for (int kt = 0; kt < NT; kt += 2) {
    if (kt + 2 < NT) LOAD((kt + 2) * 64, ga0, gb0, sa0);
    COMPUTE(0);
    WRITE(ga1, gb1, sa1, 1, (kt + 1) * 64);
    __syncthreads();
    if (kt + 3 < NT) LOAD((kt + 3) * 64, ga1, gb1, sa1);
    COMPUTE(1);
    if (kt + 2 < NT) WRITE(ga0, gb0, sa0, 0, (kt + 2) * 64);
    __syncthreads();
  }

  if (MODE == 2) {
#pragma unroll
    for (int i = 0; i < 2; ++i)
#pragma unroll
      for (int j = 0; j < 2; ++j)
#pragma unroll
        for (int q = 0; q < 4; ++q) {
          int row = r0 + wr * 32 + i * 16 + lg * 4 + q;
          int col = c0 + wc * 32 + j * 16 + l15;
          Sout[((long)b * E_ + row) * D_ + col] = acc[i][j][q];
        }
#pragma unroll
    for (int j = 0; j < 2; ++j) {
      float m = -3.0e38f;
#pragma unroll
      for (int i = 0; i < 2; ++i)
#pragma unroll
        for (int q = 0; q < 4; ++q) m = fmaxf(m, acc[i][j][q]);
      m = fmaxf(m, __shfl_xor(m, 16));
      m = fmaxf(m, __shfl_xor(m, 32));
      float ssum = 0.f;
#pragma unroll
      for (int i = 0; i < 2; ++i)
#pragma unroll
        for (int q = 0; q < 4; ++q) ssum += __expf(acc[i][j][q] - m);
      ssum += __shfl_xor(ssum, 16);
      ssum += __shfl_xor(ssum, 32);
      if (lg == 0) {
        sM[wr][wc * 32 + j * 16 + l15] = m;
        sS[wr][wc * 32 + j * 16 + l15] = ssum;
      }
    }
    __syncthreads();
    if (t < 64) {
      float m0 = sM[0][t], m1 = sM[1][t];
      float M = fmaxf(m0, m1);
      float ss = sS[0][t] * __expf(m0 - M) + sS[1][t] * __expf(m1 - M);
      int idx = (b * 16 + y) * D_ + c0 + t;
      mxp[idx] = M;
      smp[idx] = ss;
    }
  } else {
    float al = *alphap, oneal = 1.0f - al;
#pragma unroll
    for (int i = 0; i < 2; ++i)
#pragma unroll
      for (int j = 0; j < 2; ++j)
#pragma unroll
        for (int q = 0; q < 4; ++q) {
          int row = r0 + wr * 32 + i * 16 + lg * 4 + q;
          int col = c0 + wc * 32 + j * 16 + l15;
          long idx = ((long)b * E_ + row) * D_ + col;
          outEF[idx] = al * edge[idx] + oneal * acc[i][j][q];
        }
  }
}

// ---------- combine 16 row-segments of column stats; sv = 1/sum ----------
__global__ __launch_bounds__(256) void k_cstats2(const float* __restrict__ mxp, const float* __restrict__ smp,
                                                 float* __restrict__ mx, float* __restrict__ sv) {
  int i = blockIdx.x * 256 + threadIdx.x;  // over B_*D_
  int b = i >> 8, d = i & 255;
  float M = -3.0e38f;
#pragma unroll
  for (int s = 0; s < 16; ++s) M = fmaxf(M, mxp[(b * 16 + s) * D_ + d]);
  float S = 0.f;
#pragma unroll
  for (int s = 0; s < 16; ++s) S += smp[(b * 16 + s) * D_ + d] * __expf(mxp[(b * 16 + s) * D_ + d] - M);
  mx[i] = M;
  sv[i] = 1.0f / S;
}

// ---------- z[b][e] = ef[b][e][:] . attw ----------
__global__ __launch_bounds__(256) void k_z(const float* __restrict__ ef, const float* __restrict__ attw,
                                           float* __restrict__ z) {
  int b = blockIdx.y, e0 = blockIdx.x * 64;
  int w = threadIdx.x >> 6, l = threadIdx.x & 63;
  float4 wv = *reinterpret_cast<const float4*>(attw + l * 4);
  for (int e = e0 + w; e < e0 + 64; e += 4) {
    float4 v = *reinterpret_cast<const float4*>(ef + ((long)b * E_ + e) * D_ + l * 4);
    float p = v.x * wv.x + v.y * wv.y + v.z * wv.z + v.w * wv.w;
#pragma unroll
    for (int off = 32; off; off >>= 1) p += __shfl_down(p, off);
    if (l == 0) z[b * E_ + e] = p;
  }
}

// ---------- softmax over e of z -> az ----------
__global__ __launch_bounds__(256) void k_zsm(const float* __restrict__ z, float* __restrict__ az) {
  int b = blockIdx.x, t = threadIdx.x;
  __shared__ float wred[4];
  float4 v = *reinterpret_cast<const float4*>(z + b * E_ + t * 4);
  float m = fmaxf(fmaxf(v.x, v.y), fmaxf(v.z, v.w));
#pragma unroll
  for (int off = 32; off; off >>= 1) m = fmaxf(m, __shfl_xor(m, off));
  if ((t & 63) == 0) wred[t >> 6] = m;
  __syncthreads();
  m = fmaxf(fmaxf(wred[0], wred[1]), fmaxf(wred[2], wred[3]));
  float e0 = __expf(v.x - m), e1 = __expf(v.y - m), e2 = __expf(v.z - m), e3 = __expf(v.w - m);
  float s = e0 + e1 + e2 + e3;
#pragma unroll
  for (int off = 32; off; off >>= 1) s += __shfl_xor(s, off);
  __syncthreads();
  if ((t & 63) == 0) wred[t >> 6] = s;
  __syncthreads();
  s = wred[0] + wred[1] + wred[2] + wred[3];
  float inv = 1.0f / s;
  float4 o;
  o.x = e0 * inv; o.y = e1 * inv; o.z = e2 * inv; o.w = e3 * inv;
  *reinterpret_cast<float4*>(az + b * E_ + t * 4) = o;
}

// ---------- pooled[b][d] = sum_e az[b][e] * ef[b][e][d] ----------
__global__ __launch_bounds__(256) void k_pooled(const float* __restrict__ ef, const float* __restrict__ az,
                                                float* __restrict__ pooled) {
  int b = blockIdx.y;
  int d = blockIdx.x * 64 + (threadIdx.x & 63);
  int g = threadIdx.x >> 6;
  float a = 0.f;
  for (int e = g; e < E_; e += 4)
    a += az[b * E_ + e] * ef[((long)b * E_ + e) * D_ + d];
  __shared__ float ps[4][64];
  ps[g][threadIdx.x & 63] = a;
  __syncthreads();
  if (threadIdx.x < 64)
    pooled[b * D_ + blockIdx.x * 64 + threadIdx.x] =
        ps[0][threadIdx.x] + ps[1][threadIdx.x] + ps[2][threadIdx.x] + ps[3][threadIdx.x];
}

// ---------- out = pooled@proj^T + b ; logits = out@fc^T + fcb ----------
__global__ __launch_bounds__(256) void k_out(const float* __restrict__ pooled,
                                             const float* __restrict__ projw, const float* __restrict__ projb,
                                             const float* __restrict__ fcw, const float* __restrict__ fcb,
                                             float* __restrict__ outp) {
  int b = blockIdx.x, t = threadIdx.x;
  __shared__ float pl[D_], ov[D_];
  pl[t] = pooled[b * D_ + t];
  __syncthreads();
  float o = projb[t];
  for (int d = 0; d < D_; ++d) o += projw[t * D_ + d] * pl[d];
  ov[t] = o;
  __syncthreads();
  if (t < C_) {
    float lg = fcb[t];
    for (int d = 0; d < D_; ++d) lg += fcw[t * D_ + d] * ov[d];
    outp[b * C_ + t] = lg;
  }
}

extern "C" void kernel_launch(void* const* d_in, const int* in_sizes, int n_in,
                              void* d_out, int out_size, void* d_ws, size_t ws_size,
                              hipStream_t stream) {
  const float* node  = (const float*)d_in[0];
  const float* edge  = (const float*)d_in[1];
  const float* inc   = (const float*)d_in[2];
  const float* Wa    = (const float*)d_in[3];
  const float* Wp    = (const float*)d_in[4];
  const float* alpha = (const float*)d_in[5];
  const float* attw  = (const float*)d_in[6];
  const float* projw = (const float*)d_in[7];
  const float* projb = (const float*)d_in[8];
  const float* fcw   = (const float*)d_in[9];
  const float* fcb   = (const float*)d_in[10];
  float* outp = (float*)d_out;

  char* wsp = (char*)d_ws;
  size_t off = 0;
  auto alloc = [&](size_t bytes) {
    char* p = wsp + off;
    off += (bytes + 255) & ~(size_t)255;
    return (void*)p;
  };
  // P (32MB) is dead after k_red; S and ef alias its two 16MB halves.
  float* P  = (float*)alloc((size_t)4 * B_ * E_ * D_ * 4);
  float* S  = P;                                  // written in step 4 (after k_red)
  float* ef = P + (size_t)2 * B_ * E_ * D_;       // written in step 6
  u16* Wab  = (u16*)alloc((size_t)D_ * D_ * 2);
  u16* Wpb  = (u16*)alloc((size_t)D_ * D_ * 2);
  u16* G    = (u16*)alloc((size_t)B_ * E_ * D_ * 2);
  float* mxp = (float*)alloc((size_t)B_ * 16 * D_ * 4);
  float* smp = (float*)alloc((size_t)B_ * 16 * D_ * 4);
  float* mx  = (float*)alloc((size_t)B_ * D_ * 4);
  float* sv  = (float*)alloc((size_t)B_ * D_ * 4);
  float* z   = (float*)alloc((size_t)B_ * E_ * 4);
  float* az  = (float*)alloc((size_t)B_ * E_ * 4);
  float* pooled = (float*)alloc((size_t)B_ * D_ * 4);

  // 1. convert Wa, Wp to bf16
  k_cvt2<<<dim3(D_ * D_ / 1024), 256, 0, stream>>>(Wa, Wab, Wp, Wpb, D_ * D_);
  // 2. split-K partial GEMM: P[kc] = inc^T @ nf over m-chunks
  k_gemm0<<<dim3(256), 512, 0, stream>>>(inc, node, P);
  // 3. reduce partials -> G bf16
  k_red<<<dim3((B_ * E_ * D_) / 1024), 256, 0, stream>>>(P, G);
  // 4. S = G @ Wa^T (f32) + partial column softmax stats (16 segs)
  k_gemmS<2><<<dim3(512), 256, 0, stream>>>(G, Wab, nullptr, nullptr, nullptr,
                                            S, mxp, smp, nullptr, nullptr, nullptr);
  // 5. combine stats -> mx, sv(=1/sum)
  k_cstats2<<<dim3(B_ * D_ / 256), 256, 0, stream>>>(mxp, smp, mx, sv);
  // 6. ef = alpha*edge + (1-alpha) * ((G*softmax) @ Wp^T), H fused in staging
  k_gemmS<1><<<dim3(512), 256, 0, stream>>>(G, Wpb, S, mx, sv,
                                            nullptr, nullptr, nullptr, edge, alpha, ef);
  // 7-10. edge attention pooling + final projections
  k_z<<<dim3(E_ / 64, B_), 256, 0, stream>>>(ef, attw, z);
  k_zsm<<<dim3(B_), 256, 0, stream>>>(z, az);
  k_pooled<<<dim3(D_ / 64, B_), 256, 0, stream>>>(ef, az, pooled);
  k_out<<<dim3(B_), 256, 0, stream>>>(pooled, projw, projb, fcw, fcb, outp);
}